// Round 12
// baseline (150.267 us; speedup 1.0000x reference)
//
#include <hip/hip_runtime.h>
#include <math.h>

typedef __bf16 bf16x8 __attribute__((ext_vector_type(8)));
typedef float f32x4 __attribute__((ext_vector_type(4)));
typedef unsigned short u16;
typedef __attribute__((address_space(3))) unsigned int lds_u32;
typedef const __attribute__((address_space(1))) unsigned int glb_u32;

// ---------------- helpers ----------------
__device__ __forceinline__ u16 f2bf(float f) {
    unsigned int u = __builtin_bit_cast(unsigned int, f);
    unsigned int r = (u + 0x7FFFu + ((u >> 16) & 1u)) >> 16;   // RNE
    return (u16)r;
}
__device__ __forceinline__ float bf2f(u16 u) {
    unsigned int v = ((unsigned int)u) << 16;
    return __builtin_bit_cast(float, v);
}
__device__ __forceinline__ unsigned int pack2(float a, float b) {
    return (unsigned int)f2bf(a) | ((unsigned int)f2bf(b) << 16);
}
__device__ __forceinline__ bf16x8 ld8(const u16* p) {
    uint4 u = *reinterpret_cast<const uint4*>(p);
    return __builtin_bit_cast(bf16x8, u);
}
__device__ __forceinline__ void gload_lds16(const u16* g, u16* l) {
#if __has_builtin(__builtin_amdgcn_global_load_lds)
    __builtin_amdgcn_global_load_lds((glb_u32*)g, (lds_u32*)l, 16, 0, 0);
#else
    *reinterpret_cast<uint4*>(l) = *reinterpret_cast<const uint4*>(g);
#endif
}

// ---------------- preproc device pieces (each consumes one 256-thr unit) ----
__device__ __forceinline__ void dev_zero(u16* base, int nimg, int C, int B, int tid) {
    int idx = B * 256 + tid;
    int c8 = C >> 3;
    int tot = nimg * 516 * c8;
    if (idx >= tot) return;
    int cb = idx % c8;
    int t = idx / c8;
    int pb = t % 516;
    int img = t / 516;
    int y, x;
    if (pb < 130)      { y = 0;        x = pb; }
    else if (pb < 260) { y = 129;      x = pb - 130; }
    else if (pb < 388) { y = pb - 259; x = 0; }
    else               { y = pb - 387; x = 129; }
    u16* d = base + ((size_t)img * 16900 + (size_t)y * 130 + x) * C + cb * 8;
    uint4 z = {0u, 0u, 0u, 0u};
    *reinterpret_cast<uint4*>(d) = z;
}

// mode 0: dst[o*9*Cin + kk*Cin + ci]; mode 1: dst[o*576 + (ci>>3)*72 + kk*8 + (ci&7)]
__device__ __forceinline__ void dev_repack(const float* w, u16* dst,
                                           int Cout, int Cin, int mode, int B, int tid) {
    int idx = B * 256 + tid;
    int total = Cout * Cin * 9;
    if (idx >= total) return;
    int kk = idx % 9;
    int t = idx / 9;
    int ci = t % Cin;
    int o = t / Cin;
    u16 v = f2bf(w[idx]);
    size_t d;
    if (mode == 0) d = (size_t)o * (9 * Cin) + kk * Cin + ci;
    else           d = (size_t)o * 576 + (ci >> 3) * 72 + kk * 8 + (ci & 7);
    dst[d] = v;
}

__device__ __forceinline__ void dev_to_nhwc(const float* src, u16* dst,
                                            int c0, int Ctot, int B, int tid) {
    int idx = B * 256 + tid;
    int pix = idx & 16383, b = idx >> 14;
    int y = pix >> 7, x = pix & 127;
    const float* s = src + (size_t)b * 64 * 16384 + pix;
    u16* d = dst + (((size_t)b * 16900) + (size_t)(y + 1) * 130 + (x + 1)) * Ctot + c0;
#pragma unroll
    for (int q = 0; q < 8; ++q) {
        float v0 = s[(size_t)(q * 8 + 0) * 16384], v1 = s[(size_t)(q * 8 + 1) * 16384];
        float v2 = s[(size_t)(q * 8 + 2) * 16384], v3 = s[(size_t)(q * 8 + 3) * 16384];
        float v4 = s[(size_t)(q * 8 + 4) * 16384], v5 = s[(size_t)(q * 8 + 5) * 16384];
        float v6 = s[(size_t)(q * 8 + 6) * 16384], v7 = s[(size_t)(q * 8 + 7) * 16384];
        uint4 u;
        u.x = pack2(v0, v1); u.y = pack2(v2, v3); u.z = pack2(v4, v5); u.w = pack2(v6, v7);
        *reinterpret_cast<uint4*>(d + q * 8) = u;
    }
}

__device__ __forceinline__ void dev_up2(const float* src, u16* dst,
                                        int c0, int Ctot, float scale, int B, int tid) {
    int idx = B * 256 + tid;
    int pix = idx & 16383, b = idx >> 14;
    int y = pix >> 7, x = pix & 127;
    const float f = 63.0f / 127.0f;
    float cy = y * f, cx = x * f;
    float y0f = floorf(cy), x0f = floorf(cx);
    int y0 = (int)y0f, x0 = (int)x0f;
    int y1 = min(y0 + 1, 63), x1 = min(x0 + 1, 63);
    float fy = cy - y0f, fx = cx - x0f;
    float w00 = (1.f - fy) * (1.f - fx) * scale, w01 = (1.f - fy) * fx * scale;
    float w10 = fy * (1.f - fx) * scale, w11 = fy * fx * scale;
    int i00 = y0 * 64 + x0, i01 = y0 * 64 + x1, i10 = y1 * 64 + x0, i11 = y1 * 64 + x1;
    const float* s = src + (size_t)b * 64 * 4096;
    u16* d = dst + (((size_t)b * 16900) + (size_t)(y + 1) * 130 + (x + 1)) * Ctot + c0;
#pragma unroll
    for (int q = 0; q < 8; ++q) {
        float v[8];
#pragma unroll
        for (int c = 0; c < 8; ++c) {
            const float* p = s + (size_t)(q * 8 + c) * 4096;
            v[c] = w00 * p[i00] + w01 * p[i01] + w10 * p[i10] + w11 * p[i11];
        }
        uint4 u;
        u.x = pack2(v[0], v[1]); u.y = pack2(v[2], v[3]);
        u.z = pack2(v[4], v[5]); u.w = pack2(v[6], v[7]);
        *reinterpret_cast<uint4*>(d + q * 8) = u;
    }
}

// ---------------- one fused preprocessing dispatch (2409 blocks) ------------
__global__ __launch_bounds__(256) void preproc(
    const float* __restrict__ x, const float* __restrict__ y,
    const float* __restrict__ prev_off, const float* __restrict__ prev_fea,
    const float* __restrict__ w1, const float* __restrict__ w2,
    const float* __restrict__ w3, const float* __restrict__ w_off,
    const float* __restrict__ w_dcn, const float* __restrict__ w_fea,
    u16* __restrict__ T1, u16* __restrict__ T3, u16* __restrict__ T9,
    u16* __restrict__ T4,
    u16* __restrict__ wq1, u16* __restrict__ wq2, u16* __restrict__ wq3,
    u16* __restrict__ wqo, u16* __restrict__ wqd, u16* __restrict__ wqf) {
    int B = blockIdx.x, tid = threadIdx.x;
    if (B < 129) { dev_zero(T1, 4, 128, B, tid); return; }  B -= 129;   // T1+T3
    if (B < 65)  { dev_zero(T9, 2, 128, B, tid); return; }  B -= 65;
    if (B < 65)  { dev_zero(T4, 4, 64, B, tid); return; }   B -= 65;    // T4+T5
    if (B < 288) { dev_repack(w1, wq1, 64, 128, 0, B, tid); return; }   B -= 288;
    if (B < 288) { dev_repack(w2, wq2, 64, 128, 0, B, tid); return; }   B -= 288;
    if (B < 144) { dev_repack(w3, wq3, 64, 64, 0, B, tid); return; }    B -= 144;
    if (B < 486) { dev_repack(w_off, wqo, 216, 64, 0, B, tid); return; } B -= 486;
    if (B < 144) { dev_repack(w_dcn, wqd, 64, 64, 1, B, tid); return; } B -= 144;
    if (B < 288) { dev_repack(w_fea, wqf, 64, 128, 0, B, tid); return; } B -= 288;
    if (B < 128) { dev_to_nhwc(x, T1, 0, 128, B, tid); return; }        B -= 128;
    if (B < 128) { dev_to_nhwc(y, T1, 64, 128, B, tid); return; }       B -= 128;
    if (B < 128) { dev_up2(prev_off, T3, 64, 128, 2.0f, B, tid); return; } B -= 128;
    dev_up2(prev_fea, T9, 64, 128, 1.0f, B, tid);
}

// ---------------- barrier-free LDS-full-stage implicit-GEMM conv ------------
// ALL 9 shifts of the 64-row weight tile staged to LDS ONCE (dynamic LDS:
// 147KB @CIN=128, 73.7KB @CIN=64), then the whole 9x(CIN/32/KSPLIT) K-loop
// runs with ZERO barriers (B streams from global, A from LDS, swizzled).
// Wave decomposition: WAVES = PXW px-columns x KSPLIT K-slices.
// NCHW_MODE: 0 none, 1 fp32, 2 bf16
template<int CIN, int WAVES, int KSPLIT, int ACTM, bool NHWC_OUT, bool OUT_PAD, int NCHW_MODE>
__global__ __launch_bounds__(WAVES * 64) void conv_tile(
    const u16* __restrict__ in, const u16* __restrict__ wgt,
    const float* __restrict__ bias,
    u16* __restrict__ outN, int c0, int Ctot,
    void* __restrict__ outC, int Cout) {
    constexpr int T = WAVES * 64;
    constexpr int PXW = WAVES / KSPLIT;          // px-columns per block
    constexpr int BPR = 4 / PXW;                 // blocks per image row
    constexpr int KCH = CIN / KSPLIT;            // channels per wave
    constexpr int CSTEPS = KCH / 32;             // k-steps per shift per wave
    constexpr int MSK = (CIN == 128) ? 15 : 7;   // 16B-slots per row - 1
    constexpr int SPR = CIN / 8;                 // 16B-slots per row
    constexpr int SPS = 64 * SPR;                // 16B-slots per shift
    constexpr int NSTG = 72 * CIN / T;           // staging iters per thread (=36)
    extern __shared__ __align__(16) u16 As[];    // [9][64][CIN] swizzled

    const int tid = threadIdx.x;
    const int lane = tid & 63;
    const int wv = tid >> 6;
    const int kslice = wv % KSPLIT;
    const int pxc = wv / KSPLIT;
    const int gx = blockIdx.x;
    const int xh = gx % BPR;
    const int y = (gx / BPR) & 127;
    const int b = gx / (BPR * 128);
    const int mblk = blockIdx.y << 6;
    const int n0 = lane & 15;
    const int kq = lane >> 4;
    const int xbase = xh * (PXW * 32) + pxc * 32;

    const u16* inB = in + (size_t)b * 16900 * CIN;

    // ---- stage ALL shifts once (pre-swizzled source -> linear LDS dest) ----
#pragma unroll
    for (int i = 0; i < NSTG; ++i) {
        int ls = i * T + tid;                    // 16B-slot index
        int s = ls / SPS;
        int w = ls - s * SPS;
        int r = w / SPR;
        int c16 = w - r * SPR;
        int sc = c16 ^ (r & MSK);
        const u16* src = wgt + (size_t)(mblk + r) * (9 * CIN) + s * CIN + sc * 8;
        gload_lds16(src, &As[(size_t)ls * 8]);
    }
    __syncthreads();                             // the ONLY vmcnt-drain barrier

    f32x4 acc[4][2] = {};

#pragma unroll
    for (int s = 0; s < 9; ++s) {
        const int dy = s / 3, dx = s - dy * 3;
        const u16* brow = inB + ((size_t)(y + dy) * 130 + (xbase + n0 + dx)) * CIN
                          + kq * 8;
        const u16* ab = As + (size_t)s * (64 * CIN);
#pragma unroll
        for (int c = 0; c < CSTEPS; ++c) {
            const int kch = kslice * KCH + c * 32;
            bf16x8 b0 = ld8(brow + kch);
            bf16x8 b1 = ld8(brow + 16 * CIN + kch);
            const int colb = ((((kch >> 3) + kq)) ^ (n0 & MSK)) * 8;
            bf16x8 a0 = ld8(ab + (0 * 16 + n0) * CIN + colb);
            bf16x8 a1 = ld8(ab + (1 * 16 + n0) * CIN + colb);
            bf16x8 a2 = ld8(ab + (2 * 16 + n0) * CIN + colb);
            bf16x8 a3 = ld8(ab + (3 * 16 + n0) * CIN + colb);
            acc[0][0] = __builtin_amdgcn_mfma_f32_16x16x32_bf16(a0, b0, acc[0][0], 0, 0, 0);
            acc[0][1] = __builtin_amdgcn_mfma_f32_16x16x32_bf16(a0, b1, acc[0][1], 0, 0, 0);
            acc[1][0] = __builtin_amdgcn_mfma_f32_16x16x32_bf16(a1, b0, acc[1][0], 0, 0, 0);
            acc[1][1] = __builtin_amdgcn_mfma_f32_16x16x32_bf16(a1, b1, acc[1][1], 0, 0, 0);
            acc[2][0] = __builtin_amdgcn_mfma_f32_16x16x32_bf16(a2, b0, acc[2][0], 0, 0, 0);
            acc[2][1] = __builtin_amdgcn_mfma_f32_16x16x32_bf16(a2, b1, acc[2][1], 0, 0, 0);
            acc[3][0] = __builtin_amdgcn_mfma_f32_16x16x32_bf16(a3, b0, acc[3][0], 0, 0, 0);
            acc[3][1] = __builtin_amdgcn_mfma_f32_16x16x32_bf16(a3, b1, acc[3][1], 0, 0, 0);
        }
    }

    // 2-way K reduce (kslice 1 -> kslice 0) when split; reuses weight LDS
    if (KSPLIT == 2) {
        float* red = (float*)As;
        __syncthreads();                         // weights dead; protect reuse
        if (kslice == 1) {
#pragma unroll
            for (int mt = 0; mt < 4; ++mt)
#pragma unroll
                for (int nt = 0; nt < 2; ++nt)
                    *reinterpret_cast<f32x4*>(
                        &red[((pxc * 8) + mt * 2 + nt) * 256 + lane * 4]) = acc[mt][nt];
        }
        __syncthreads();
        if (kslice == 1) return;
#pragma unroll
        for (int mt = 0; mt < 4; ++mt)
#pragma unroll
            for (int nt = 0; nt < 2; ++nt)
                acc[mt][nt] += *reinterpret_cast<const f32x4*>(
                    &red[((pxc * 8) + mt * 2 + nt) * 256 + lane * 4]);
    }

    // epilogue: each surviving wave stores its own 32-px column, all 4 m-tiles
#pragma unroll
    for (int mt = 0; mt < 4; ++mt) {
        const int mbase = mblk + mt * 16 + kq * 4;
        float bs0 = 0.f, bs1 = 0.f, bs2 = 0.f, bs3 = 0.f;
        if (mbase < Cout) {
            bs0 = bias[mbase]; bs1 = bias[mbase + 1];
            bs2 = bias[mbase + 2]; bs3 = bias[mbase + 3];
        }
#pragma unroll
        for (int nt = 0; nt < 2; ++nt) {
            const int xx = xbase + nt * 16 + n0;
            float v0 = acc[mt][nt][0] + bs0, v1 = acc[mt][nt][1] + bs1;
            float v2 = acc[mt][nt][2] + bs2, v3 = acc[mt][nt][3] + bs3;
            if (ACTM == 1) {
                v0 = (v0 >= 0.f) ? v0 : 0.1f * v0;
                v1 = (v1 >= 0.f) ? v1 : 0.1f * v1;
                v2 = (v2 >= 0.f) ? v2 : 0.1f * v2;
                v3 = (v3 >= 0.f) ? v3 : 0.1f * v3;
            } else if (ACTM == 2) {
                if (mbase >= 144) {
                    v0 = 1.f / (1.f + expf(-v0));
                    v1 = 1.f / (1.f + expf(-v1));
                    v2 = 1.f / (1.f + expf(-v2));
                    v3 = 1.f / (1.f + expf(-v3));
                }
            }
            if (NHWC_OUT && mbase < Cout) {
                size_t pix = OUT_PAD ? ((size_t)(y + 1) * 130 + xx + 1)
                                     : ((size_t)y * 128 + xx);
                size_t off = ((size_t)b * (OUT_PAD ? 16900 : 16384) + pix) * Ctot + c0 + mbase;
                uint2 u;
                u.x = pack2(v0, v1); u.y = pack2(v2, v3);
                *reinterpret_cast<uint2*>(outN + off) = u;
            }
            if (NCHW_MODE == 1 && mbase < Cout) {
                float* oc = (float*)outC;
                size_t o = ((size_t)(b * Cout + mbase)) * 16384 + (size_t)y * 128 + xx;
                oc[o] = v0; oc[o + 16384] = v1;
                oc[o + 2 * 16384] = v2; oc[o + 3 * 16384] = v3;
            }
            if (NCHW_MODE == 2 && mbase < Cout) {
                u16* oc = (u16*)outC;
                size_t o = ((size_t)(b * Cout + mbase)) * 16384 + (size_t)y * 128 + xx;
                oc[o] = f2bf(v0); oc[o + 16384] = f2bf(v1);
                oc[o + 2 * 16384] = f2bf(v2); oc[o + 3 * 16384] = f2bf(v3);
            }
        }
    }
}

// ---------------- fused DCNv2: sample in-register + K=576 MFMA GEMM ---------
// xn : NHWC128-pad bf16 (x at ch 0..63)
// co : NCHW bf16 [b][216][16384]; ch>=144 already sigmoided
// wgt: bf16 [64][576] in sample order (g*72 + kk*8 + c)
__global__ __launch_bounds__(256, 2) void dcn_fused(
    const u16* __restrict__ xn, const u16* __restrict__ co,
    const u16* __restrict__ wgt, const float* __restrict__ bias,
    u16* __restrict__ outN) {
    __shared__ u16 lw[64 * 584];      // padded stride 584 (bank-spread)
    {
        int t = threadIdx.x;
        int o = t >> 2, chunk = t & 3;
        const u16* src = wgt + o * 576 + chunk * 144;
        u16* dst = lw + o * 584 + chunk * 144;
#pragma unroll
        for (int i = 0; i < 18; ++i)
            *reinterpret_cast<uint4*>(dst + i * 8) =
                *reinterpret_cast<const uint4*>(src + i * 8);
    }
    __syncthreads();

    const int lane = threadIdx.x & 63;
    const int wv = threadIdx.x >> 6;
    const int half = blockIdx.x & 1;
    const int y = (blockIdx.x >> 1) & 127;
    const int b = blockIdx.x >> 8;
    const int n0 = lane & 15;
    const int kq = lane >> 4;
    const int xx = half * 64 + wv * 16 + n0;
    const int p = y * 128 + xx;

    const u16* cob = co + (size_t)b * 216 * 16384 + p;
    const u16* xb = xn + (size_t)b * 16900 * 128;

    float offy[18], offx[18], mvv[18];
#pragma unroll
    for (int cs = 0; cs < 18; ++cs) {
        int gk8 = cs * 4 + kq;
        offy[cs] = bf2f(cob[(size_t)gk8 * 16384]);
        offx[cs] = bf2f(cob[(size_t)(72 + gk8) * 16384]);
        mvv[cs]  = bf2f(cob[(size_t)(144 + gk8) * 16384]);   // pre-sigmoided
    }

    f32x4 acc[4] = {};
    float w00[2], w01[2], w10[2], w11[2];
    uint4 q00[2], q01[2], q10[2], q11[2];

#define DCN_GL(cs, st) {                                                       \
        int gk8_ = (cs) * 4 + kq;                                              \
        int g_ = (gk8_ * 57) >> 9;                                             \
        int kk_ = gk8_ - 9 * g_;                                               \
        int ky_ = (kk_ * 11) >> 5;                                             \
        int kx_ = kk_ - 3 * ky_;                                               \
        float py_ = offy[cs] + (float)(ky_ - 1) + (float)y;                    \
        float px_ = offx[cs] + (float)(kx_ - 1) + (float)xx;                   \
        float y0f_ = floorf(py_), x0f_ = floorf(px_);                          \
        float wy_ = py_ - y0f_, wx_ = px_ - x0f_;                              \
        int y0_ = (int)y0f_, x0_ = (int)x0f_, y1_ = y0_ + 1, x1_ = x0_ + 1;    \
        float m00_ = ((unsigned)y0_ < 128u && (unsigned)x0_ < 128u) ? 1.f : 0.f; \
        float m01_ = ((unsigned)y0_ < 128u && (unsigned)x1_ < 128u) ? 1.f : 0.f; \
        float m10_ = ((unsigned)y1_ < 128u && (unsigned)x0_ < 128u) ? 1.f : 0.f; \
        float m11_ = ((unsigned)y1_ < 128u && (unsigned)x1_ < 128u) ? 1.f : 0.f; \
        float mv_ = mvv[cs];                                                   \
        w00[st] = (1.f - wy_) * (1.f - wx_) * m00_ * mv_;                      \
        w01[st] = (1.f - wy_) * wx_ * m01_ * mv_;                              \
        w10[st] = wy_ * (1.f - wx_) * m10_ * mv_;                              \
        w11[st] = wy_ * wx_ * m11_ * mv_;                                      \
        int y0c_ = min(max(y0_, 0), 127), y1c_ = min(max(y1_, 0), 127);        \
        int x0c_ = min(max(x0_, 0), 127), x1c_ = min(max(x1_, 0), 127);        \
        const u16* xg_ = xb + g_ * 8;                                          \
        q00[st] = *reinterpret_cast<const uint4*>(xg_ + ((size_t)(y0c_ + 1) * 130 + x0c_ + 1) * 128); \
        q01[st] = *reinterpret_cast<const uint4*>(xg_ + ((size_t)(y0c_ + 1) * 130 + x1c_ + 1) * 128); \
        q10[st] = *reinterpret_cast<const uint4*>(xg_ + ((size_t)(y1c_ + 1) * 130 + x0c_ + 1) * 128); \
        q11[st] = *reinterpret_cast<const uint4*>(xg_ + ((size_t)(y1c_ + 1) * 130 + x1c_ + 1) * 128); \
    }

#define DCN_GU(cs, st) {                                                       \
        const unsigned int* a00_ = &q00[st].x; const unsigned int* a01_ = &q01[st].x; \
        const unsigned int* a10_ = &q10[st].x; const unsigned int* a11_ = &q11[st].x; \
        float r_[8];                                                           \
        _Pragma("unroll")                                                      \
        for (int c = 0; c < 8; ++c) {                                          \
            unsigned int u00_ = a00_[c >> 1], u01_ = a01_[c >> 1];             \
            unsigned int u10_ = a10_[c >> 1], u11_ = a11_[c >> 1];             \
            int sh_ = (c & 1) * 16;                                            \
            float f00_ = bf2f((u16)(u00_ >> sh_)), f01_ = bf2f((u16)(u01_ >> sh_)); \
            float f10_ = bf2f((u16)(u10_ >> sh_)), f11_ = bf2f((u16)(u11_ >> sh_)); \
            r_[c] = w00[st] * f00_ + w01[st] * f01_ + w10[st] * f10_ + w11[st] * f11_; \
        }                                                                      \
        uint4 bu_;                                                             \
        bu_.x = pack2(r_[0], r_[1]); bu_.y = pack2(r_[2], r_[3]);              \
        bu_.z = pack2(r_[4], r_[5]); bu_.w = pack2(r_[6], r_[7]);              \
        bf16x8 bfrag_ = __builtin_bit_cast(bf16x8, bu_);                       \
        const int kcol_ = (cs) * 32 + kq * 8;                                  \
        bf16x8 a0_ = ld8(lw + (size_t)(0 * 16 + n0) * 584 + kcol_);            \
        bf16x8 a1_ = ld8(lw + (size_t)(1 * 16 + n0) * 584 + kcol_);            \
        bf16x8 a2_ = ld8(lw + (size_t)(2 * 16 + n0) * 584 + kcol_);            \
        bf16x8 a3_ = ld8(lw + (size_t)(3 * 16 + n0) * 584 + kcol_);            \
        acc[0] = __builtin_amdgcn_mfma_f32_16x16x32_bf16(a0_, bfrag_, acc[0], 0, 0, 0); \
        acc[1] = __builtin_amdgcn_mfma_f32_16x16x32_bf16(a1_, bfrag_, acc[1], 0, 0, 0); \
        acc[2] = __builtin_amdgcn_mfma_f32_16x16x32_bf16(a2_, bfrag_, acc[2], 0, 0, 0); \
        acc[3] = __builtin_amdgcn_mfma_f32_16x16x32_bf16(a3_, bfrag_, acc[3], 0, 0, 0); \
    }

    DCN_GL(0, 0)
    DCN_GL(1, 1)
#pragma unroll
    for (int cs = 0; cs < 18; cs += 2) {
        DCN_GU(cs, 0)
        if (cs + 2 < 18) DCN_GL(cs + 2, 0)
        DCN_GU(cs + 1, 1)
        if (cs + 3 < 18) DCN_GL(cs + 3, 1)
    }
#undef DCN_GL
#undef DCN_GU

    // epilogue: fea -> NHWC128-pad ch0..63
#pragma unroll
    for (int mt = 0; mt < 4; ++mt) {
        const int mbase = mt * 16 + kq * 4;
        float v0 = acc[mt][0] + bias[mbase];
        float v1 = acc[mt][1] + bias[mbase + 1];
        float v2 = acc[mt][2] + bias[mbase + 2];
        float v3 = acc[mt][3] + bias[mbase + 3];
        size_t off = ((size_t)b * 16900 + (size_t)(y + 1) * 130 + (xx + 1)) * 128 + mbase;
        uint2 u;
        u.x = pack2(v0, v1); u.y = pack2(v2, v3);
        *reinterpret_cast<uint2*>(outN + off) = u;
    }
}

// ---------------- workspace layout (bytes) ----------------------------------
#define T1_OFF 0u            /* NHWC128-pad x||y                 8,652,800 */
#define T3_OFF 8652800u      /* NHWC128-pad off1||upPrev         8,652,800 */
#define T9_OFF 17305600u     /* NHWC128-pad fea||upFea           8,652,800 */
#define T4_OFF 25958400u     /* NHWC64-pad off2                  4,326,400 */
#define T5_OFF 30284800u     /* NHWC64-pad off                   4,326,400 */
#define T6_OFF 34611200u     /* co bf16 NCHW [2][216][16384]    14,155,776 */
#define W1_OFF 48766976u
#define W2_OFF 48914432u
#define W3_OFF 49061888u
#define WF_OFF 49135616u
#define WO_OFF 49283072u     /* padded to 256 rows: 294,912 B */
#define WD_OFF 49577984u     /* ends 49,651,712 */

extern "C" void kernel_launch(void* const* d_in, const int* in_sizes, int n_in,
                              void* d_out, int out_size, void* d_ws, size_t ws_size,
                              hipStream_t stream) {
    const float* x        = (const float*)d_in[0];
    const float* y        = (const float*)d_in[1];
    const float* prev_off = (const float*)d_in[2];
    const float* prev_fea = (const float*)d_in[3];
    const float* w1 = (const float*)d_in[4];  const float* b1 = (const float*)d_in[5];
    const float* w2 = (const float*)d_in[6];  const float* b2 = (const float*)d_in[7];
    const float* w3 = (const float*)d_in[8];  const float* b3 = (const float*)d_in[9];
    const float* w_off = (const float*)d_in[10]; const float* b_off = (const float*)d_in[11];
    const float* w_dcn = (const float*)d_in[12]; const float* b_dcn = (const float*)d_in[13];
    const float* w_fea = (const float*)d_in[14]; const float* b_fea = (const float*)d_in[15];

    float* out_off = (float*)d_out;
    float* out_out = (float*)d_out + (size_t)2 * 64 * 16384;

    char* ws = (char*)d_ws;
    u16* T1 = (u16*)(ws + T1_OFF);
    u16* T3 = (u16*)(ws + T3_OFF);
    u16* T9 = (u16*)(ws + T9_OFF);
    u16* T4 = (u16*)(ws + T4_OFF);
    u16* T5 = (u16*)(ws + T5_OFF);
    u16* T6 = (u16*)(ws + T6_OFF);
    u16* wq1 = (u16*)(ws + W1_OFF);
    u16* wq2 = (u16*)(ws + W2_OFF);
    u16* wq3 = (u16*)(ws + W3_OFF);
    u16* wqf = (u16*)(ws + WF_OFF);
    u16* wqo = (u16*)(ws + WO_OFF);
    u16* wqd = (u16*)(ws + WD_OFF);
    // (wqo pad rows 216..255 never written: consumer stores masked mbase<Cout;
    //  poison bf16 is finite — deterministic, cannot leak)

    // opt-in to >64KB dynamic LDS for the full-stage conv kernels (idempotent)
    auto kA = (const void*)conv_tile<128, 4, 2, 1, true, true, 0>;
    auto kF = (const void*)conv_tile<128, 4, 2, 1, false, false, 1>;
    auto k3 = (const void*)conv_tile<64, 2, 1, 1, true, true, 1>;
    auto kO = (const void*)conv_tile<64, 2, 1, 2, false, false, 2>;
    hipFuncSetAttribute(kA, hipFuncAttributeMaxDynamicSharedMemorySize, 147456);
    hipFuncSetAttribute(kF, hipFuncAttributeMaxDynamicSharedMemorySize, 147456);
    hipFuncSetAttribute(k3, hipFuncAttributeMaxDynamicSharedMemorySize, 73728);
    hipFuncSetAttribute(kO, hipFuncAttributeMaxDynamicSharedMemorySize, 73728);

    // 1. all independent preprocessing in ONE dispatch
    preproc<<<dim3(2409), dim3(256), 0, stream>>>(
        x, y, prev_off, prev_fea, w1, w2, w3, w_off, w_dcn, w_fea,
        T1, T3, T9, T4, wq1, wq2, wq3, wqo, wqd, wqf);

    // 2. conv1: concat(x,y) -> off1 (T3 ch0..63)
    conv_tile<128, 4, 2, 1, true, true, 0><<<dim3(512, 1), dim3(256), 147456, stream>>>(
        T1, wq1, b1, T3, 0, 128, nullptr, 64);
    // 3. conv2: concat(off1, upPrev*2) -> off2 (T4)
    conv_tile<128, 4, 2, 1, true, true, 0><<<dim3(512, 1), dim3(256), 147456, stream>>>(
        T3, wq2, b2, T4, 0, 64, nullptr, 64);
    // 4. conv3: off2 -> off (T5 + output0 NCHW fp32)
    conv_tile<64, 2, 1, 1, true, true, 1><<<dim3(512, 1), dim3(128), 73728, stream>>>(
        T4, wq3, b3, T5, 0, 64, out_off, 64);
    // 5. conv_off: off -> co NCHW bf16, sigmoid on ch>=144
    conv_tile<64, 2, 1, 2, false, false, 2><<<dim3(512, 4), dim3(128), 73728, stream>>>(
        T5, wqo, b_off, nullptr, 0, 0, T6, 216);
    // 6. fused DCN: sample + K=576 GEMM -> fea (T9 ch0..63)
    dcn_fused<<<dim3(512), dim3(256), 0, stream>>>(T1, T6, wqd, b_dcn, T9);
    // 7. final conv: concat(fea, upFea) -> output1 NCHW fp32
    conv_tile<128, 4, 2, 1, false, false, 1><<<dim3(512, 1), dim3(256), 147456, stream>>>(
        T9, wqf, b_fea, nullptr, 0, 0, out_out, 64);
}

// Round 13
// 146.319 us; speedup vs baseline: 1.0270x; 1.0270x over previous
//
#include <hip/hip_runtime.h>
#include <math.h>

typedef __bf16 bf16x8 __attribute__((ext_vector_type(8)));
typedef float f32x4 __attribute__((ext_vector_type(4)));
typedef unsigned short u16;
typedef __attribute__((address_space(3))) unsigned int lds_u32;
typedef const __attribute__((address_space(1))) unsigned int glb_u32;

// ---------------- helpers ----------------
__device__ __forceinline__ u16 f2bf(float f) {
    unsigned int u = __builtin_bit_cast(unsigned int, f);
    unsigned int r = (u + 0x7FFFu + ((u >> 16) & 1u)) >> 16;   // RNE
    return (u16)r;
}
__device__ __forceinline__ float bf2f(u16 u) {
    unsigned int v = ((unsigned int)u) << 16;
    return __builtin_bit_cast(float, v);
}
__device__ __forceinline__ unsigned int pack2(float a, float b) {
    return (unsigned int)f2bf(a) | ((unsigned int)f2bf(b) << 16);
}
__device__ __forceinline__ bf16x8 ld8(const u16* p) {
    uint4 u = *reinterpret_cast<const uint4*>(p);
    return __builtin_bit_cast(bf16x8, u);
}
__device__ __forceinline__ void gload_lds16(const u16* g, u16* l) {
#if __has_builtin(__builtin_amdgcn_global_load_lds)
    __builtin_amdgcn_global_load_lds((glb_u32*)g, (lds_u32*)l, 16, 0, 0);
#else
    *reinterpret_cast<uint4*>(l) = *reinterpret_cast<const uint4*>(g);
#endif
}

// ---------------- preproc device pieces (each consumes one 256-thr unit) ----
__device__ __forceinline__ void dev_zero(u16* base, int nimg, int C, int B, int tid) {
    int idx = B * 256 + tid;
    int c8 = C >> 3;
    int tot = nimg * 516 * c8;
    if (idx >= tot) return;
    int cb = idx % c8;
    int t = idx / c8;
    int pb = t % 516;
    int img = t / 516;
    int y, x;
    if (pb < 130)      { y = 0;        x = pb; }
    else if (pb < 260) { y = 129;      x = pb - 130; }
    else if (pb < 388) { y = pb - 259; x = 0; }
    else               { y = pb - 387; x = 129; }
    u16* d = base + ((size_t)img * 16900 + (size_t)y * 130 + x) * C + cb * 8;
    uint4 z = {0u, 0u, 0u, 0u};
    *reinterpret_cast<uint4*>(d) = z;
}

// mode 0: dst[o*9*Cin + kk*Cin + ci]; mode 1: dst[o*576 + (ci>>3)*72 + kk*8 + (ci&7)]
__device__ __forceinline__ void dev_repack(const float* w, u16* dst,
                                           int Cout, int Cin, int mode, int B, int tid) {
    int idx = B * 256 + tid;
    int total = Cout * Cin * 9;
    if (idx >= total) return;
    int kk = idx % 9;
    int t = idx / 9;
    int ci = t % Cin;
    int o = t / Cin;
    u16 v = f2bf(w[idx]);
    size_t d;
    if (mode == 0) d = (size_t)o * (9 * Cin) + kk * Cin + ci;
    else           d = (size_t)o * 576 + (ci >> 3) * 72 + kk * 8 + (ci & 7);
    dst[d] = v;
}

// 4 consecutive pixels per thread; float4 loads (4x fewer VMEM instructions)
__device__ __forceinline__ void dev_to_nhwc4(const float* src, u16* dst,
                                             int c0, int Ctot, int B, int tid) {
    int idx = B * 256 + tid;                  // 8192 pixel-groups (2 batches)
    int b = idx >> 12;
    int p0 = (idx & 4095) * 4;
    int y = p0 >> 7, x = p0 & 127;
    const float* s = src + (size_t)b * 64 * 16384 + p0;
    u16* dbase = dst + (((size_t)b * 16900) + (size_t)(y + 1) * 130 + (x + 1)) * Ctot + c0;
#pragma unroll
    for (int q = 0; q < 8; ++q) {
        float4 f[8];
#pragma unroll
        for (int c = 0; c < 8; ++c)
            f[c] = *reinterpret_cast<const float4*>(s + (size_t)(q * 8 + c) * 16384);
        const float* fp = (const float*)f;
#pragma unroll
        for (int j = 0; j < 4; ++j) {
            uint4 u;
            u.x = pack2(fp[0 * 4 + j], fp[1 * 4 + j]);
            u.y = pack2(fp[2 * 4 + j], fp[3 * 4 + j]);
            u.z = pack2(fp[4 * 4 + j], fp[5 * 4 + j]);
            u.w = pack2(fp[6 * 4 + j], fp[7 * 4 + j]);
            *reinterpret_cast<uint4*>(dbase + (size_t)j * Ctot + q * 8) = u;
        }
    }
}

__device__ __forceinline__ void dev_up2(const float* src, u16* dst,
                                        int c0, int Ctot, float scale, int B, int tid) {
    int idx = B * 256 + tid;
    int pix = idx & 16383, b = idx >> 14;
    int y = pix >> 7, x = pix & 127;
    const float f = 63.0f / 127.0f;
    float cy = y * f, cx = x * f;
    float y0f = floorf(cy), x0f = floorf(cx);
    int y0 = (int)y0f, x0 = (int)x0f;
    int y1 = min(y0 + 1, 63), x1 = min(x0 + 1, 63);
    float fy = cy - y0f, fx = cx - x0f;
    float w00 = (1.f - fy) * (1.f - fx) * scale, w01 = (1.f - fy) * fx * scale;
    float w10 = fy * (1.f - fx) * scale, w11 = fy * fx * scale;
    int i00 = y0 * 64 + x0, i01 = y0 * 64 + x1, i10 = y1 * 64 + x0, i11 = y1 * 64 + x1;
    const float* s = src + (size_t)b * 64 * 4096;
    u16* d = dst + (((size_t)b * 16900) + (size_t)(y + 1) * 130 + (x + 1)) * Ctot + c0;
#pragma unroll
    for (int q = 0; q < 8; ++q) {
        float v[8];
#pragma unroll
        for (int c = 0; c < 8; ++c) {
            const float* p = s + (size_t)(q * 8 + c) * 4096;
            v[c] = w00 * p[i00] + w01 * p[i01] + w10 * p[i10] + w11 * p[i11];
        }
        uint4 u;
        u.x = pack2(v[0], v[1]); u.y = pack2(v[2], v[3]);
        u.z = pack2(v[4], v[5]); u.w = pack2(v[6], v[7]);
        *reinterpret_cast<uint4*>(d + q * 8) = u;
    }
}

// ---------------- one fused preprocessing dispatch (2217 blocks) ------------
__global__ __launch_bounds__(256) void preproc(
    const float* __restrict__ x, const float* __restrict__ y,
    const float* __restrict__ prev_off, const float* __restrict__ prev_fea,
    const float* __restrict__ w1, const float* __restrict__ w2,
    const float* __restrict__ w3, const float* __restrict__ w_off,
    const float* __restrict__ w_dcn, const float* __restrict__ w_fea,
    u16* __restrict__ T1, u16* __restrict__ T3, u16* __restrict__ T9,
    u16* __restrict__ T4,
    u16* __restrict__ wq1, u16* __restrict__ wq2, u16* __restrict__ wq3,
    u16* __restrict__ wqo, u16* __restrict__ wqd, u16* __restrict__ wqf) {
    int B = blockIdx.x, tid = threadIdx.x;
    if (B < 129) { dev_zero(T1, 4, 128, B, tid); return; }  B -= 129;   // T1+T3
    if (B < 65)  { dev_zero(T9, 2, 128, B, tid); return; }  B -= 65;
    if (B < 65)  { dev_zero(T4, 4, 64, B, tid); return; }   B -= 65;    // T4+T5
    if (B < 288) { dev_repack(w1, wq1, 64, 128, 0, B, tid); return; }   B -= 288;
    if (B < 288) { dev_repack(w2, wq2, 64, 128, 0, B, tid); return; }   B -= 288;
    if (B < 144) { dev_repack(w3, wq3, 64, 64, 0, B, tid); return; }    B -= 144;
    if (B < 486) { dev_repack(w_off, wqo, 216, 64, 0, B, tid); return; } B -= 486;
    if (B < 144) { dev_repack(w_dcn, wqd, 64, 64, 1, B, tid); return; } B -= 144;
    if (B < 288) { dev_repack(w_fea, wqf, 64, 128, 0, B, tid); return; } B -= 288;
    if (B < 32)  { dev_to_nhwc4(x, T1, 0, 128, B, tid); return; }       B -= 32;
    if (B < 32)  { dev_to_nhwc4(y, T1, 64, 128, B, tid); return; }      B -= 32;
    if (B < 128) { dev_up2(prev_off, T3, 64, 128, 2.0f, B, tid); return; } B -= 128;
    dev_up2(prev_fea, T9, 64, 128, 1.0f, B, tid);
}

// ---------------- LDS-staged implicit-GEMM conv via MFMA (R11-proven) -------
// Wave decomposition: WAVES = PXW px-columns x KSPLIT K-slices.
// NCHW_MODE: 0 none, 1 fp32, 2 bf16
template<int CIN, int WAVES, int KSPLIT, int ACTM, bool NHWC_OUT, bool OUT_PAD, int NCHW_MODE>
__global__ __launch_bounds__(WAVES * 64) void conv_tile(
    const u16* __restrict__ in, const u16* __restrict__ wgt,
    const float* __restrict__ bias,
    u16* __restrict__ outN, int c0, int Ctot,
    void* __restrict__ outC, int Cout) {
    constexpr int T = WAVES * 64;
    constexpr int PXW = WAVES / KSPLIT;          // px-columns per block
    constexpr int BPR = 4 / PXW;                 // blocks per image row
    constexpr int KCH = CIN / KSPLIT;            // channels per wave
    constexpr int CSTEPS = KCH / 32;             // k-steps per shift per wave
    constexpr int MSK = (CIN == 128) ? 15 : 7;   // 16B-slots per row - 1
    constexpr int RSH = (CIN == 128) ? 8 : 7;    // log2(row bytes)
    __shared__ __align__(16) u16 As[2][64 * CIN];

    const int tid = threadIdx.x;
    const int lane = tid & 63;
    const int wv = tid >> 6;
    const int kslice = wv % KSPLIT;
    const int pxc = wv / KSPLIT;
    const int gx = blockIdx.x;
    const int xh = gx % BPR;
    const int y = (gx / BPR) & 127;
    const int b = gx / (BPR * 128);
    const int mblk = blockIdx.y << 6;
    const int n0 = lane & 15;
    const int kq = lane >> 4;
    const int xbase = xh * (PXW * 32) + pxc * 32;

    const u16* inB = in + (size_t)b * 16900 * CIN;

#define STAGE(ss, bf) {                                                        \
        _Pragma("unroll")                                                      \
        for (int i_ = 0; i_ < (8 * CIN) / T; ++i_) {                           \
            int L_ = (i_ * T + tid) * 16;                                      \
            int row_ = L_ >> RSH;                                              \
            int c16_ = (L_ >> 4) & MSK;                                        \
            int sc_ = c16_ ^ (row_ & MSK);                                     \
            const u16* src_ = wgt + (size_t)(mblk + row_) * (9 * CIN)          \
                              + (ss) * CIN + sc_ * 8;                          \
            gload_lds16(src_, &As[bf][L_ >> 1]);                               \
        }                                                                      \
    }

    f32x4 acc[4][2] = {};

    STAGE(0, 0)
    __syncthreads();

    for (int s = 0; s < 9; ++s) {
        const int buf = s & 1;
        if (s < 8) STAGE(s + 1, buf ^ 1)

        const int dy = s / 3, dx = s - dy * 3;
        const u16* brow = inB + ((size_t)(y + dy) * 130 + (xbase + n0 + dx)) * CIN
                          + kq * 8;
        const u16* ab = &As[buf][0];
#pragma unroll
        for (int c = 0; c < CSTEPS; ++c) {
            const int kch = kslice * KCH + c * 32;
            bf16x8 b0 = ld8(brow + kch);
            bf16x8 b1 = ld8(brow + 16 * CIN + kch);
            const int colb = (((kch >> 3) + kq) ^ (n0 & MSK)) * 8;
            bf16x8 a0 = ld8(ab + (0 * 16 + n0) * CIN + colb);
            bf16x8 a1 = ld8(ab + (1 * 16 + n0) * CIN + colb);
            bf16x8 a2 = ld8(ab + (2 * 16 + n0) * CIN + colb);
            bf16x8 a3 = ld8(ab + (3 * 16 + n0) * CIN + colb);
            acc[0][0] = __builtin_amdgcn_mfma_f32_16x16x32_bf16(a0, b0, acc[0][0], 0, 0, 0);
            acc[0][1] = __builtin_amdgcn_mfma_f32_16x16x32_bf16(a0, b1, acc[0][1], 0, 0, 0);
            acc[1][0] = __builtin_amdgcn_mfma_f32_16x16x32_bf16(a1, b0, acc[1][0], 0, 0, 0);
            acc[1][1] = __builtin_amdgcn_mfma_f32_16x16x32_bf16(a1, b1, acc[1][1], 0, 0, 0);
            acc[2][0] = __builtin_amdgcn_mfma_f32_16x16x32_bf16(a2, b0, acc[2][0], 0, 0, 0);
            acc[2][1] = __builtin_amdgcn_mfma_f32_16x16x32_bf16(a2, b1, acc[2][1], 0, 0, 0);
            acc[3][0] = __builtin_amdgcn_mfma_f32_16x16x32_bf16(a3, b0, acc[3][0], 0, 0, 0);
            acc[3][1] = __builtin_amdgcn_mfma_f32_16x16x32_bf16(a3, b1, acc[3][1], 0, 0, 0);
        }
        __syncthreads();
    }
#undef STAGE

    // 2-way K reduce (kslice 1 -> kslice 0) when split
    if (KSPLIT == 2) {
        float* red = (float*)(&As[0][0]);
        if (kslice == 1) {
#pragma unroll
            for (int mt = 0; mt < 4; ++mt)
#pragma unroll
                for (int nt = 0; nt < 2; ++nt)
                    *reinterpret_cast<f32x4*>(
                        &red[((pxc * 8) + mt * 2 + nt) * 256 + lane * 4]) = acc[mt][nt];
        }
        __syncthreads();
        if (kslice == 1) return;
#pragma unroll
        for (int mt = 0; mt < 4; ++mt)
#pragma unroll
            for (int nt = 0; nt < 2; ++nt)
                acc[mt][nt] += *reinterpret_cast<const f32x4*>(
                    &red[((pxc * 8) + mt * 2 + nt) * 256 + lane * 4]);
    }

    // epilogue: each surviving wave stores its own 32-px column, all 4 m-tiles
#pragma unroll
    for (int mt = 0; mt < 4; ++mt) {
        const int mbase = mblk + mt * 16 + kq * 4;
        float bs0 = 0.f, bs1 = 0.f, bs2 = 0.f, bs3 = 0.f;
        if (mbase < Cout) {
            bs0 = bias[mbase]; bs1 = bias[mbase + 1];
            bs2 = bias[mbase + 2]; bs3 = bias[mbase + 3];
        }
#pragma unroll
        for (int nt = 0; nt < 2; ++nt) {
            const int xx = xbase + nt * 16 + n0;
            float v0 = acc[mt][nt][0] + bs0, v1 = acc[mt][nt][1] + bs1;
            float v2 = acc[mt][nt][2] + bs2, v3 = acc[mt][nt][3] + bs3;
            if (ACTM == 1) {
                v0 = (v0 >= 0.f) ? v0 : 0.1f * v0;
                v1 = (v1 >= 0.f) ? v1 : 0.1f * v1;
                v2 = (v2 >= 0.f) ? v2 : 0.1f * v2;
                v3 = (v3 >= 0.f) ? v3 : 0.1f * v3;
            } else if (ACTM == 2) {
                if (mbase >= 144) {
                    v0 = 1.f / (1.f + expf(-v0));
                    v1 = 1.f / (1.f + expf(-v1));
                    v2 = 1.f / (1.f + expf(-v2));
                    v3 = 1.f / (1.f + expf(-v3));
                }
            }
            if (NHWC_OUT && mbase < Cout) {
                size_t pix = OUT_PAD ? ((size_t)(y + 1) * 130 + xx + 1)
                                     : ((size_t)y * 128 + xx);
                size_t off = ((size_t)b * (OUT_PAD ? 16900 : 16384) + pix) * Ctot + c0 + mbase;
                uint2 u;
                u.x = pack2(v0, v1); u.y = pack2(v2, v3);
                *reinterpret_cast<uint2*>(outN + off) = u;
            }
            if (NCHW_MODE == 1 && mbase < Cout) {
                float* oc = (float*)outC;
                size_t o = ((size_t)(b * Cout + mbase)) * 16384 + (size_t)y * 128 + xx;
                oc[o] = v0; oc[o + 16384] = v1;
                oc[o + 2 * 16384] = v2; oc[o + 3 * 16384] = v3;
            }
            if (NCHW_MODE == 2 && mbase < Cout) {
                u16* oc = (u16*)outC;
                size_t o = ((size_t)(b * Cout + mbase)) * 16384 + (size_t)y * 128 + xx;
                oc[o] = f2bf(v0); oc[o + 16384] = f2bf(v1);
                oc[o + 2 * 16384] = f2bf(v2); oc[o + 3 * 16384] = f2bf(v3);
            }
        }
    }
}

// ---------------- fused DCNv2: sample in-register + K=576 MFMA GEMM ---------
// xn : NHWC128-pad bf16 (x at ch 0..63)
// co : NCHW bf16 [b][216][16384]; ch>=144 already sigmoided
// wgt: bf16 [64][576] in sample order (g*72 + kk*8 + c)
__global__ __launch_bounds__(256, 2) void dcn_fused(
    const u16* __restrict__ xn, const u16* __restrict__ co,
    const u16* __restrict__ wgt, const float* __restrict__ bias,
    u16* __restrict__ outN) {
    __shared__ u16 lw[64 * 584];      // padded stride 584 (bank-spread)
    {
        int t = threadIdx.x;
        int o = t >> 2, chunk = t & 3;
        const u16* src = wgt + o * 576 + chunk * 144;
        u16* dst = lw + o * 584 + chunk * 144;
#pragma unroll
        for (int i = 0; i < 18; ++i)
            *reinterpret_cast<uint4*>(dst + i * 8) =
                *reinterpret_cast<const uint4*>(src + i * 8);
    }
    __syncthreads();

    const int lane = threadIdx.x & 63;
    const int wv = threadIdx.x >> 6;
    const int half = blockIdx.x & 1;
    const int y = (blockIdx.x >> 1) & 127;
    const int b = blockIdx.x >> 8;
    const int n0 = lane & 15;
    const int kq = lane >> 4;
    const int xx = half * 64 + wv * 16 + n0;
    const int p = y * 128 + xx;

    const u16* cob = co + (size_t)b * 216 * 16384 + p;
    const u16* xb = xn + (size_t)b * 16900 * 128;

    float offy[18], offx[18], mvv[18];
#pragma unroll
    for (int cs = 0; cs < 18; ++cs) {
        int gk8 = cs * 4 + kq;
        offy[cs] = bf2f(cob[(size_t)gk8 * 16384]);
        offx[cs] = bf2f(cob[(size_t)(72 + gk8) * 16384]);
        mvv[cs]  = bf2f(cob[(size_t)(144 + gk8) * 16384]);   // pre-sigmoided
    }

    f32x4 acc[4] = {};
    float w00[2], w01[2], w10[2], w11[2];
    uint4 q00[2], q01[2], q10[2], q11[2];

#define DCN_GL(cs, st) {                                                       \
        int gk8_ = (cs) * 4 + kq;                                              \
        int g_ = (gk8_ * 57) >> 9;                                             \
        int kk_ = gk8_ - 9 * g_;                                               \
        int ky_ = (kk_ * 11) >> 5;                                             \
        int kx_ = kk_ - 3 * ky_;                                               \
        float py_ = offy[cs] + (float)(ky_ - 1) + (float)y;                    \
        float px_ = offx[cs] + (float)(kx_ - 1) + (float)xx;                   \
        float y0f_ = floorf(py_), x0f_ = floorf(px_);                          \
        float wy_ = py_ - y0f_, wx_ = px_ - x0f_;                              \
        int y0_ = (int)y0f_, x0_ = (int)x0f_, y1_ = y0_ + 1, x1_ = x0_ + 1;    \
        float m00_ = ((unsigned)y0_ < 128u && (unsigned)x0_ < 128u) ? 1.f : 0.f; \
        float m01_ = ((unsigned)y0_ < 128u && (unsigned)x1_ < 128u) ? 1.f : 0.f; \
        float m10_ = ((unsigned)y1_ < 128u && (unsigned)x0_ < 128u) ? 1.f : 0.f; \
        float m11_ = ((unsigned)y1_ < 128u && (unsigned)x1_ < 128u) ? 1.f : 0.f; \
        float mv_ = mvv[cs];                                                   \
        w00[st] = (1.f - wy_) * (1.f - wx_) * m00_ * mv_;                      \
        w01[st] = (1.f - wy_) * wx_ * m01_ * mv_;                              \
        w10[st] = wy_ * (1.f - wx_) * m10_ * mv_;                              \
        w11[st] = wy_ * wx_ * m11_ * mv_;                                      \
        int y0c_ = min(max(y0_, 0), 127), y1c_ = min(max(y1_, 0), 127);        \
        int x0c_ = min(max(x0_, 0), 127), x1c_ = min(max(x1_, 0), 127);        \
        const u16* xg_ = xb + g_ * 8;                                          \
        q00[st] = *reinterpret_cast<const uint4*>(xg_ + ((size_t)(y0c_ + 1) * 130 + x0c_ + 1) * 128); \
        q01[st] = *reinterpret_cast<const uint4*>(xg_ + ((size_t)(y0c_ + 1) * 130 + x1c_ + 1) * 128); \
        q10[st] = *reinterpret_cast<const uint4*>(xg_ + ((size_t)(y1c_ + 1) * 130 + x0c_ + 1) * 128); \
        q11[st] = *reinterpret_cast<const uint4*>(xg_ + ((size_t)(y1c_ + 1) * 130 + x1c_ + 1) * 128); \
    }

#define DCN_GU(cs, st) {                                                       \
        const unsigned int* a00_ = &q00[st].x; const unsigned int* a01_ = &q01[st].x; \
        const unsigned int* a10_ = &q10[st].x; const unsigned int* a11_ = &q11[st].x; \
        float r_[8];                                                           \
        _Pragma("unroll")                                                      \
        for (int c = 0; c < 8; ++c) {                                          \
            unsigned int u00_ = a00_[c >> 1], u01_ = a01_[c >> 1];             \
            unsigned int u10_ = a10_[c >> 1], u11_ = a11_[c >> 1];             \
            int sh_ = (c & 1) * 16;                                            \
            float f00_ = bf2f((u16)(u00_ >> sh_)), f01_ = bf2f((u16)(u01_ >> sh_)); \
            float f10_ = bf2f((u16)(u10_ >> sh_)), f11_ = bf2f((u16)(u11_ >> sh_)); \
            r_[c] = w00[st] * f00_ + w01[st] * f01_ + w10[st] * f10_ + w11[st] * f11_; \
        }                                                                      \
        uint4 bu_;                                                             \
        bu_.x = pack2(r_[0], r_[1]); bu_.y = pack2(r_[2], r_[3]);              \
        bu_.z = pack2(r_[4], r_[5]); bu_.w = pack2(r_[6], r_[7]);              \
        bf16x8 bfrag_ = __builtin_bit_cast(bf16x8, bu_);                       \
        const int kcol_ = (cs) * 32 + kq * 8;                                  \
        bf16x8 a0_ = ld8(lw + (size_t)(0 * 16 + n0) * 584 + kcol_);            \
        bf16x8 a1_ = ld8(lw + (size_t)(1 * 16 + n0) * 584 + kcol_);            \
        bf16x8 a2_ = ld8(lw + (size_t)(2 * 16 + n0) * 584 + kcol_);            \
        bf16x8 a3_ = ld8(lw + (size_t)(3 * 16 + n0) * 584 + kcol_);            \
        acc[0] = __builtin_amdgcn_mfma_f32_16x16x32_bf16(a0_, bfrag_, acc[0], 0, 0, 0); \
        acc[1] = __builtin_amdgcn_mfma_f32_16x16x32_bf16(a1_, bfrag_, acc[1], 0, 0, 0); \
        acc[2] = __builtin_amdgcn_mfma_f32_16x16x32_bf16(a2_, bfrag_, acc[2], 0, 0, 0); \
        acc[3] = __builtin_amdgcn_mfma_f32_16x16x32_bf16(a3_, bfrag_, acc[3], 0, 0, 0); \
    }

    DCN_GL(0, 0)
    DCN_GL(1, 1)
#pragma unroll
    for (int cs = 0; cs < 18; cs += 2) {
        DCN_GU(cs, 0)
        if (cs + 2 < 18) DCN_GL(cs + 2, 0)
        DCN_GU(cs + 1, 1)
        if (cs + 3 < 18) DCN_GL(cs + 3, 1)
    }
#undef DCN_GL
#undef DCN_GU

    // epilogue: fea -> NHWC128-pad ch0..63
#pragma unroll
    for (int mt = 0; mt < 4; ++mt) {
        const int mbase = mt * 16 + kq * 4;
        float v0 = acc[mt][0] + bias[mbase];
        float v1 = acc[mt][1] + bias[mbase + 1];
        float v2 = acc[mt][2] + bias[mbase + 2];
        float v3 = acc[mt][3] + bias[mbase + 3];
        size_t off = ((size_t)b * 16900 + (size_t)(y + 1) * 130 + (xx + 1)) * 128 + mbase;
        uint2 u;
        u.x = pack2(v0, v1); u.y = pack2(v2, v3);
        *reinterpret_cast<uint2*>(outN + off) = u;
    }
}

// ---------------- workspace layout (bytes) ----------------------------------
#define T1_OFF 0u            /* NHWC128-pad x||y                 8,652,800 */
#define T3_OFF 8652800u      /* NHWC128-pad off1||upPrev         8,652,800 */
#define T9_OFF 17305600u     /* NHWC128-pad fea||upFea           8,652,800 */
#define T4_OFF 25958400u     /* NHWC64-pad off2                  4,326,400 */
#define T5_OFF 30284800u     /* NHWC64-pad off                   4,326,400 */
#define T6_OFF 34611200u     /* co bf16 NCHW [2][216][16384]    14,155,776 */
#define W1_OFF 48766976u
#define W2_OFF 48914432u
#define W3_OFF 49061888u
#define WF_OFF 49135616u
#define WO_OFF 49283072u     /* padded to 256 rows: 294,912 B */
#define WD_OFF 49577984u     /* ends 49,651,712 */

extern "C" void kernel_launch(void* const* d_in, const int* in_sizes, int n_in,
                              void* d_out, int out_size, void* d_ws, size_t ws_size,
                              hipStream_t stream) {
    const float* x        = (const float*)d_in[0];
    const float* y        = (const float*)d_in[1];
    const float* prev_off = (const float*)d_in[2];
    const float* prev_fea = (const float*)d_in[3];
    const float* w1 = (const float*)d_in[4];  const float* b1 = (const float*)d_in[5];
    const float* w2 = (const float*)d_in[6];  const float* b2 = (const float*)d_in[7];
    const float* w3 = (const float*)d_in[8];  const float* b3 = (const float*)d_in[9];
    const float* w_off = (const float*)d_in[10]; const float* b_off = (const float*)d_in[11];
    const float* w_dcn = (const float*)d_in[12]; const float* b_dcn = (const float*)d_in[13];
    const float* w_fea = (const float*)d_in[14]; const float* b_fea = (const float*)d_in[15];

    float* out_off = (float*)d_out;
    float* out_out = (float*)d_out + (size_t)2 * 64 * 16384;

    char* ws = (char*)d_ws;
    u16* T1 = (u16*)(ws + T1_OFF);
    u16* T3 = (u16*)(ws + T3_OFF);
    u16* T9 = (u16*)(ws + T9_OFF);
    u16* T4 = (u16*)(ws + T4_OFF);
    u16* T5 = (u16*)(ws + T5_OFF);
    u16* T6 = (u16*)(ws + T6_OFF);
    u16* wq1 = (u16*)(ws + W1_OFF);
    u16* wq2 = (u16*)(ws + W2_OFF);
    u16* wq3 = (u16*)(ws + W3_OFF);
    u16* wqf = (u16*)(ws + WF_OFF);
    u16* wqo = (u16*)(ws + WO_OFF);
    u16* wqd = (u16*)(ws + WD_OFF);
    // (wqo pad rows 216..255 never written: consumer stores masked mbase<Cout;
    //  poison bf16 is finite — deterministic, cannot leak)

    // 1. all independent preprocessing in ONE dispatch
    preproc<<<dim3(2217), dim3(256), 0, stream>>>(
        x, y, prev_off, prev_fea, w1, w2, w3, w_off, w_dcn, w_fea,
        T1, T3, T9, T4, wq1, wq2, wq3, wqo, wqd, wqf);

    // 2. conv1: concat(x,y) -> off1 (T3 ch0..63)   [512 blocks, 2px x 2K waves]
    conv_tile<128, 4, 2, 1, true, true, 0><<<dim3(512, 1), dim3(256), 0, stream>>>(
        T1, wq1, b1, T3, 0, 128, nullptr, 64);
    // 3. conv2: concat(off1, upPrev*2) -> off2 (T4)
    conv_tile<128, 4, 2, 1, true, true, 0><<<dim3(512, 1), dim3(256), 0, stream>>>(
        T3, wq2, b2, T4, 0, 64, nullptr, 64);
    // 4. conv3: off2 -> off (T5 + output0 NCHW fp32)  [full-K waves, no reduce]
    conv_tile<64, 2, 1, 1, true, true, 1><<<dim3(512, 1), dim3(128), 0, stream>>>(
        T4, wq3, b3, T5, 0, 64, out_off, 64);
    // 5. conv_off: off -> co NCHW bf16, sigmoid on ch>=144
    conv_tile<64, 2, 1, 2, false, false, 2><<<dim3(512, 4), dim3(128), 0, stream>>>(
        T5, wqo, b_off, nullptr, 0, 0, T6, 216);
    // 6. fused DCN: sample + K=576 GEMM -> fea (T9 ch0..63)
    dcn_fused<<<dim3(512), dim3(256), 0, stream>>>(T1, T6, wqd, b_dcn, T9);
    // 7. final conv: concat(fea, upFea) -> output1 NCHW fp32
    conv_tile<128, 4, 2, 1, false, false, 1><<<dim3(512, 1), dim3(256), 0, stream>>>(
        T9, wqf, b_fea, nullptr, 0, 0, out_out, 64);
}

// Round 14
// 136.356 us; speedup vs baseline: 1.1020x; 1.0731x over previous
//
#include <hip/hip_runtime.h>
#include <math.h>

typedef __bf16 bf16x8 __attribute__((ext_vector_type(8)));
typedef float f32x4 __attribute__((ext_vector_type(4)));
typedef unsigned short u16;
typedef __attribute__((address_space(3))) unsigned int lds_u32;
typedef const __attribute__((address_space(1))) unsigned int glb_u32;

// ---------------- helpers ----------------
__device__ __forceinline__ u16 f2bf(float f) {
    unsigned int u = __builtin_bit_cast(unsigned int, f);
    unsigned int r = (u + 0x7FFFu + ((u >> 16) & 1u)) >> 16;   // RNE
    return (u16)r;
}
__device__ __forceinline__ float bf2f(u16 u) {
    unsigned int v = ((unsigned int)u) << 16;
    return __builtin_bit_cast(float, v);
}
__device__ __forceinline__ unsigned int pack2(float a, float b) {
    return (unsigned int)f2bf(a) | ((unsigned int)f2bf(b) << 16);
}
__device__ __forceinline__ bf16x8 ld8(const u16* p) {
    uint4 u = *reinterpret_cast<const uint4*>(p);
    return __builtin_bit_cast(bf16x8, u);
}
__device__ __forceinline__ void gload_lds16(const u16* g, u16* l) {
#if __has_builtin(__builtin_amdgcn_global_load_lds)
    __builtin_amdgcn_global_load_lds((glb_u32*)g, (lds_u32*)l, 16, 0, 0);
#else
    *reinterpret_cast<uint4*>(l) = *reinterpret_cast<const uint4*>(g);
#endif
}

// ---------------- preproc device pieces ----------------
__device__ __forceinline__ void dev_zero(u16* base, int nimg, int C, int B, int tid) {
    int idx = B * 256 + tid;
    int c8 = C >> 3;
    int tot = nimg * 516 * c8;
    if (idx >= tot) return;
    int cb = idx % c8;
    int t = idx / c8;
    int pb = t % 516;
    int img = t / 516;
    int y, x;
    if (pb < 130)      { y = 0;        x = pb; }
    else if (pb < 260) { y = 129;      x = pb - 130; }
    else if (pb < 388) { y = pb - 259; x = 0; }
    else               { y = pb - 387; x = 129; }
    u16* d = base + ((size_t)img * 16900 + (size_t)y * 130 + x) * C + cb * 8;
    uint4 z = {0u, 0u, 0u, 0u};
    *reinterpret_cast<uint4*>(d) = z;
}

// mode 0: dst[o*9*Cin + kk*Cin + ci]; mode 1: dst[o*576 + (ci>>3)*72 + kk*8 + (ci&7)]
__device__ __forceinline__ void dev_repack(const float* w, u16* dst,
                                           int Cout, int Cin, int mode, int B, int tid) {
    int idx = B * 256 + tid;
    int total = Cout * Cin * 9;
    if (idx >= total) return;
    int kk = idx % 9;
    int t = idx / 9;
    int ci = t % Cin;
    int o = t / Cin;
    u16 v = f2bf(w[idx]);
    size_t d;
    if (mode == 0) d = (size_t)o * (9 * Cin) + kk * Cin + ci;
    else           d = (size_t)o * 576 + (ci >> 3) * 72 + kk * 8 + (ci & 7);
    dst[d] = v;
}

// NCHW->NHWC: 4 px x 8 ch per thread; 256 blocks per tensor.
// B in [0,256): b=B>>7, rem=B&127, q=rem>>4 (channel octet), px-block=rem&15
__device__ __forceinline__ void dev_to_nhwc8(const float* src, u16* dst,
                                             int c0, int Ctot, int B, int tid) {
    int b = B >> 7;
    int rem = B & 127;
    int q = rem >> 4;
    int p0 = ((rem & 15) * 256 + tid) * 4;        // pixel base, 4 consecutive
    int y = p0 >> 7, x = p0 & 127;
    const float* s = src + ((size_t)b * 64 + q * 8) * 16384 + p0;
    u16* dbase = dst + (((size_t)b * 16900) + (size_t)(y + 1) * 130 + (x + 1)) * Ctot
                 + c0 + q * 8;
    float4 f[8];
#pragma unroll
    for (int c = 0; c < 8; ++c)
        f[c] = *reinterpret_cast<const float4*>(s + (size_t)c * 16384);
    const float* fp = (const float*)f;
#pragma unroll
    for (int j = 0; j < 4; ++j) {
        uint4 u;
        u.x = pack2(fp[0 * 4 + j], fp[1 * 4 + j]);
        u.y = pack2(fp[2 * 4 + j], fp[3 * 4 + j]);
        u.z = pack2(fp[4 * 4 + j], fp[5 * 4 + j]);
        u.w = pack2(fp[6 * 4 + j], fp[7 * 4 + j]);
        *reinterpret_cast<uint4*>(dbase + (size_t)j * Ctot + 0) = u;
        dbase += 0;  // (clarity)
        if (j < 3) {} // stores at dbase + j*Ctot handled above via index
    }
}

// bilinear up2: 1 px x 8 ch per thread; 1024 blocks per tensor.
// B in [0,1024): b=B>>9, rem=B&511, q=rem>>6 (channel octet), px-block=rem&63
__device__ __forceinline__ void dev_up2_8(const float* src, u16* dst,
                                          int c0, int Ctot, float scale, int B, int tid) {
    int b = B >> 9;
    int rem = B & 511;
    int q = rem >> 6;
    int pix = (rem & 63) * 256 + tid;
    int y = pix >> 7, x = pix & 127;
    const float f = 63.0f / 127.0f;
    float cy = y * f, cx = x * f;
    float y0f = floorf(cy), x0f = floorf(cx);
    int y0 = (int)y0f, x0 = (int)x0f;
    int y1 = min(y0 + 1, 63), x1 = min(x0 + 1, 63);
    float fy = cy - y0f, fx = cx - x0f;
    float w00 = (1.f - fy) * (1.f - fx) * scale, w01 = (1.f - fy) * fx * scale;
    float w10 = fy * (1.f - fx) * scale, w11 = fy * fx * scale;
    int i00 = y0 * 64 + x0, i01 = y0 * 64 + x1, i10 = y1 * 64 + x0, i11 = y1 * 64 + x1;
    const float* s = src + ((size_t)b * 64 + q * 8) * 4096;
    float v[8];
#pragma unroll
    for (int c = 0; c < 8; ++c) {
        const float* p = s + (size_t)c * 4096;
        v[c] = w00 * p[i00] + w01 * p[i01] + w10 * p[i10] + w11 * p[i11];
    }
    uint4 u;
    u.x = pack2(v[0], v[1]); u.y = pack2(v[2], v[3]);
    u.z = pack2(v[4], v[5]); u.w = pack2(v[6], v[7]);
    u16* d = dst + (((size_t)b * 16900) + (size_t)(y + 1) * 130 + (x + 1)) * Ctot
             + c0 + q * 8;
    *reinterpret_cast<uint4*>(d) = u;
}

// ---------------- one fused preprocessing dispatch (4457 blocks) ------------
__global__ __launch_bounds__(256) void preproc(
    const float* __restrict__ x, const float* __restrict__ y,
    const float* __restrict__ prev_off, const float* __restrict__ prev_fea,
    const float* __restrict__ w1, const float* __restrict__ w2,
    const float* __restrict__ w3, const float* __restrict__ w_off,
    const float* __restrict__ w_dcn, const float* __restrict__ w_fea,
    u16* __restrict__ T1, u16* __restrict__ T3, u16* __restrict__ T9,
    u16* __restrict__ T4,
    u16* __restrict__ wq1, u16* __restrict__ wq2, u16* __restrict__ wq3,
    u16* __restrict__ wqo, u16* __restrict__ wqd, u16* __restrict__ wqf) {
    int B = blockIdx.x, tid = threadIdx.x;
    if (B < 1024) { dev_up2_8(prev_off, T3, 64, 128, 2.0f, B, tid); return; } B -= 1024;
    if (B < 1024) { dev_up2_8(prev_fea, T9, 64, 128, 1.0f, B, tid); return; } B -= 1024;
    if (B < 256) { dev_to_nhwc8(x, T1, 0, 128, B, tid); return; }       B -= 256;
    if (B < 256) { dev_to_nhwc8(y, T1, 64, 128, B, tid); return; }      B -= 256;
    if (B < 129) { dev_zero(T1, 4, 128, B, tid); return; }  B -= 129;   // T1+T3
    if (B < 65)  { dev_zero(T9, 2, 128, B, tid); return; }  B -= 65;
    if (B < 65)  { dev_zero(T4, 4, 64, B, tid); return; }   B -= 65;    // T4+T5
    if (B < 288) { dev_repack(w1, wq1, 64, 128, 0, B, tid); return; }   B -= 288;
    if (B < 288) { dev_repack(w2, wq2, 64, 128, 0, B, tid); return; }   B -= 288;
    if (B < 144) { dev_repack(w3, wq3, 64, 64, 0, B, tid); return; }    B -= 144;
    if (B < 486) { dev_repack(w_off, wqo, 216, 64, 0, B, tid); return; } B -= 486;
    if (B < 144) { dev_repack(w_dcn, wqd, 64, 64, 1, B, tid); return; } B -= 144;
    dev_repack(w_fea, wqf, 64, 128, 0, B, tid);
}

// ---------------- LDS-staged implicit-GEMM conv via MFMA (R11-proven) -------
// Wave decomposition: WAVES = PXW px-columns x KSPLIT K-slices.
// NCHW_MODE: 0 none, 1 fp32, 2 bf16
template<int CIN, int WAVES, int KSPLIT, int ACTM, bool NHWC_OUT, bool OUT_PAD, int NCHW_MODE>
__global__ __launch_bounds__(WAVES * 64) void conv_tile(
    const u16* __restrict__ in, const u16* __restrict__ wgt,
    const float* __restrict__ bias,
    u16* __restrict__ outN, int c0, int Ctot,
    void* __restrict__ outC, int Cout) {
    constexpr int T = WAVES * 64;
    constexpr int PXW = WAVES / KSPLIT;          // px-columns per block
    constexpr int BPR = 4 / PXW;                 // blocks per image row
    constexpr int KCH = CIN / KSPLIT;            // channels per wave
    constexpr int CSTEPS = KCH / 32;             // k-steps per shift per wave
    constexpr int MSK = (CIN == 128) ? 15 : 7;   // 16B-slots per row - 1
    constexpr int RSH = (CIN == 128) ? 8 : 7;    // log2(row bytes)
    __shared__ __align__(16) u16 As[2][64 * CIN];

    const int tid = threadIdx.x;
    const int lane = tid & 63;
    const int wv = tid >> 6;
    const int kslice = wv % KSPLIT;
    const int pxc = wv / KSPLIT;
    const int gx = blockIdx.x;
    const int xh = gx % BPR;
    const int y = (gx / BPR) & 127;
    const int b = gx / (BPR * 128);
    const int mblk = blockIdx.y << 6;
    const int n0 = lane & 15;
    const int kq = lane >> 4;
    const int xbase = xh * (PXW * 32) + pxc * 32;

    const u16* inB = in + (size_t)b * 16900 * CIN;

#define STAGE(ss, bf) {                                                        \
        _Pragma("unroll")                                                      \
        for (int i_ = 0; i_ < (8 * CIN) / T; ++i_) {                           \
            int L_ = (i_ * T + tid) * 16;                                      \
            int row_ = L_ >> RSH;                                              \
            int c16_ = (L_ >> 4) & MSK;                                        \
            int sc_ = c16_ ^ (row_ & MSK);                                     \
            const u16* src_ = wgt + (size_t)(mblk + row_) * (9 * CIN)          \
                              + (ss) * CIN + sc_ * 8;                          \
            gload_lds16(src_, &As[bf][L_ >> 1]);                               \
        }                                                                      \
    }

    f32x4 acc[4][2] = {};

    STAGE(0, 0)
    __syncthreads();

    for (int s = 0; s < 9; ++s) {
        const int buf = s & 1;
        if (s < 8) STAGE(s + 1, buf ^ 1)

        const int dy = s / 3, dx = s - dy * 3;
        const u16* brow = inB + ((size_t)(y + dy) * 130 + (xbase + n0 + dx)) * CIN
                          + kq * 8;
        const u16* ab = &As[buf][0];
#pragma unroll
        for (int c = 0; c < CSTEPS; ++c) {
            const int kch = kslice * KCH + c * 32;
            bf16x8 b0 = ld8(brow + kch);
            bf16x8 b1 = ld8(brow + 16 * CIN + kch);
            const int colb = (((kch >> 3) + kq) ^ (n0 & MSK)) * 8;
            bf16x8 a0 = ld8(ab + (0 * 16 + n0) * CIN + colb);
            bf16x8 a1 = ld8(ab + (1 * 16 + n0) * CIN + colb);
            bf16x8 a2 = ld8(ab + (2 * 16 + n0) * CIN + colb);
            bf16x8 a3 = ld8(ab + (3 * 16 + n0) * CIN + colb);
            acc[0][0] = __builtin_amdgcn_mfma_f32_16x16x32_bf16(a0, b0, acc[0][0], 0, 0, 0);
            acc[0][1] = __builtin_amdgcn_mfma_f32_16x16x32_bf16(a0, b1, acc[0][1], 0, 0, 0);
            acc[1][0] = __builtin_amdgcn_mfma_f32_16x16x32_bf16(a1, b0, acc[1][0], 0, 0, 0);
            acc[1][1] = __builtin_amdgcn_mfma_f32_16x16x32_bf16(a1, b1, acc[1][1], 0, 0, 0);
            acc[2][0] = __builtin_amdgcn_mfma_f32_16x16x32_bf16(a2, b0, acc[2][0], 0, 0, 0);
            acc[2][1] = __builtin_amdgcn_mfma_f32_16x16x32_bf16(a2, b1, acc[2][1], 0, 0, 0);
            acc[3][0] = __builtin_amdgcn_mfma_f32_16x16x32_bf16(a3, b0, acc[3][0], 0, 0, 0);
            acc[3][1] = __builtin_amdgcn_mfma_f32_16x16x32_bf16(a3, b1, acc[3][1], 0, 0, 0);
        }
        __syncthreads();
    }
#undef STAGE

    // 2-way K reduce (kslice 1 -> kslice 0) when split
    if (KSPLIT == 2) {
        float* red = (float*)(&As[0][0]);
        if (kslice == 1) {
#pragma unroll
            for (int mt = 0; mt < 4; ++mt)
#pragma unroll
                for (int nt = 0; nt < 2; ++nt)
                    *reinterpret_cast<f32x4*>(
                        &red[((pxc * 8) + mt * 2 + nt) * 256 + lane * 4]) = acc[mt][nt];
        }
        __syncthreads();
        if (kslice == 1) return;
#pragma unroll
        for (int mt = 0; mt < 4; ++mt)
#pragma unroll
            for (int nt = 0; nt < 2; ++nt)
                acc[mt][nt] += *reinterpret_cast<const f32x4*>(
                    &red[((pxc * 8) + mt * 2 + nt) * 256 + lane * 4]);
    }

    // epilogue: each surviving wave stores its own 32-px column, all 4 m-tiles
#pragma unroll
    for (int mt = 0; mt < 4; ++mt) {
        const int mbase = mblk + mt * 16 + kq * 4;
        float bs0 = 0.f, bs1 = 0.f, bs2 = 0.f, bs3 = 0.f;
        if (mbase < Cout) {
            bs0 = bias[mbase]; bs1 = bias[mbase + 1];
            bs2 = bias[mbase + 2]; bs3 = bias[mbase + 3];
        }
#pragma unroll
        for (int nt = 0; nt < 2; ++nt) {
            const int xx = xbase + nt * 16 + n0;
            float v0 = acc[mt][nt][0] + bs0, v1 = acc[mt][nt][1] + bs1;
            float v2 = acc[mt][nt][2] + bs2, v3 = acc[mt][nt][3] + bs3;
            if (ACTM == 1) {
                v0 = (v0 >= 0.f) ? v0 : 0.1f * v0;
                v1 = (v1 >= 0.f) ? v1 : 0.1f * v1;
                v2 = (v2 >= 0.f) ? v2 : 0.1f * v2;
                v3 = (v3 >= 0.f) ? v3 : 0.1f * v3;
            } else if (ACTM == 2) {
                if (mbase >= 144) {
                    v0 = 1.f / (1.f + expf(-v0));
                    v1 = 1.f / (1.f + expf(-v1));
                    v2 = 1.f / (1.f + expf(-v2));
                    v3 = 1.f / (1.f + expf(-v3));
                }
            }
            if (NHWC_OUT && mbase < Cout) {
                size_t pix = OUT_PAD ? ((size_t)(y + 1) * 130 + xx + 1)
                                     : ((size_t)y * 128 + xx);
                size_t off = ((size_t)b * (OUT_PAD ? 16900 : 16384) + pix) * Ctot + c0 + mbase;
                uint2 u;
                u.x = pack2(v0, v1); u.y = pack2(v2, v3);
                *reinterpret_cast<uint2*>(outN + off) = u;
            }
            if (NCHW_MODE == 1 && mbase < Cout) {
                float* oc = (float*)outC;
                size_t o = ((size_t)(b * Cout + mbase)) * 16384 + (size_t)y * 128 + xx;
                oc[o] = v0; oc[o + 16384] = v1;
                oc[o + 2 * 16384] = v2; oc[o + 3 * 16384] = v3;
            }
            if (NCHW_MODE == 2 && mbase < Cout) {
                u16* oc = (u16*)outC;
                size_t o = ((size_t)(b * Cout + mbase)) * 16384 + (size_t)y * 128 + xx;
                oc[o] = f2bf(v0); oc[o + 16384] = f2bf(v1);
                oc[o + 2 * 16384] = f2bf(v2); oc[o + 3 * 16384] = f2bf(v3);
            }
        }
    }
}

// ---------------- fused DCNv2: sample in-register + K=576 MFMA GEMM ---------
// xn : NHWC128-pad bf16 (x at ch 0..63)
// co : NCHW bf16 [b][216][16384]; ch>=144 already sigmoided
// wgt: bf16 [64][576] in sample order (g*72 + kk*8 + c)
__global__ __launch_bounds__(256, 2) void dcn_fused(
    const u16* __restrict__ xn, const u16* __restrict__ co,
    const u16* __restrict__ wgt, const float* __restrict__ bias,
    u16* __restrict__ outN) {
    __shared__ u16 lw[64 * 584];      // padded stride 584 (bank-spread)
    {
        int t = threadIdx.x;
        int o = t >> 2, chunk = t & 3;
        const u16* src = wgt + o * 576 + chunk * 144;
        u16* dst = lw + o * 584 + chunk * 144;
#pragma unroll
        for (int i = 0; i < 18; ++i)
            *reinterpret_cast<uint4*>(dst + i * 8) =
                *reinterpret_cast<const uint4*>(src + i * 8);
    }
    __syncthreads();

    const int lane = threadIdx.x & 63;
    const int wv = threadIdx.x >> 6;
    const int half = blockIdx.x & 1;
    const int y = (blockIdx.x >> 1) & 127;
    const int b = blockIdx.x >> 8;
    const int n0 = lane & 15;
    const int kq = lane >> 4;
    const int xx = half * 64 + wv * 16 + n0;
    const int p = y * 128 + xx;

    const u16* cob = co + (size_t)b * 216 * 16384 + p;
    const u16* xb = xn + (size_t)b * 16900 * 128;

    float offy[18], offx[18], mvv[18];
#pragma unroll
    for (int cs = 0; cs < 18; ++cs) {
        int gk8 = cs * 4 + kq;
        offy[cs] = bf2f(cob[(size_t)gk8 * 16384]);
        offx[cs] = bf2f(cob[(size_t)(72 + gk8) * 16384]);
        mvv[cs]  = bf2f(cob[(size_t)(144 + gk8) * 16384]);   // pre-sigmoided
    }

    f32x4 acc[4] = {};
    float w00[2], w01[2], w10[2], w11[2];
    uint4 q00[2], q01[2], q10[2], q11[2];

#define DCN_GL(cs, st) {                                                       \
        int gk8_ = (cs) * 4 + kq;                                              \
        int g_ = (gk8_ * 57) >> 9;                                             \
        int kk_ = gk8_ - 9 * g_;                                               \
        int ky_ = (kk_ * 11) >> 5;                                             \
        int kx_ = kk_ - 3 * ky_;                                               \
        float py_ = offy[cs] + (float)(ky_ - 1) + (float)y;                    \
        float px_ = offx[cs] + (float)(kx_ - 1) + (float)xx;                   \
        float y0f_ = floorf(py_), x0f_ = floorf(px_);                          \
        float wy_ = py_ - y0f_, wx_ = px_ - x0f_;                              \
        int y0_ = (int)y0f_, x0_ = (int)x0f_, y1_ = y0_ + 1, x1_ = x0_ + 1;    \
        float m00_ = ((unsigned)y0_ < 128u && (unsigned)x0_ < 128u) ? 1.f : 0.f; \
        float m01_ = ((unsigned)y0_ < 128u && (unsigned)x1_ < 128u) ? 1.f : 0.f; \
        float m10_ = ((unsigned)y1_ < 128u && (unsigned)x0_ < 128u) ? 1.f : 0.f; \
        float m11_ = ((unsigned)y1_ < 128u && (unsigned)x1_ < 128u) ? 1.f : 0.f; \
        float mv_ = mvv[cs];                                                   \
        w00[st] = (1.f - wy_) * (1.f - wx_) * m00_ * mv_;                      \
        w01[st] = (1.f - wy_) * wx_ * m01_ * mv_;                              \
        w10[st] = wy_ * (1.f - wx_) * m10_ * mv_;                              \
        w11[st] = wy_ * wx_ * m11_ * mv_;                                      \
        int y0c_ = min(max(y0_, 0), 127), y1c_ = min(max(y1_, 0), 127);        \
        int x0c_ = min(max(x0_, 0), 127), x1c_ = min(max(x1_, 0), 127);        \
        const u16* xg_ = xb + g_ * 8;                                          \
        q00[st] = *reinterpret_cast<const uint4*>(xg_ + ((size_t)(y0c_ + 1) * 130 + x0c_ + 1) * 128); \
        q01[st] = *reinterpret_cast<const uint4*>(xg_ + ((size_t)(y0c_ + 1) * 130 + x1c_ + 1) * 128); \
        q10[st] = *reinterpret_cast<const uint4*>(xg_ + ((size_t)(y1c_ + 1) * 130 + x0c_ + 1) * 128); \
        q11[st] = *reinterpret_cast<const uint4*>(xg_ + ((size_t)(y1c_ + 1) * 130 + x1c_ + 1) * 128); \
    }

#define DCN_GU(cs, st) {                                                       \
        const unsigned int* a00_ = &q00[st].x; const unsigned int* a01_ = &q01[st].x; \
        const unsigned int* a10_ = &q10[st].x; const unsigned int* a11_ = &q11[st].x; \
        float r_[8];                                                           \
        _Pragma("unroll")                                                      \
        for (int c = 0; c < 8; ++c) {                                          \
            unsigned int u00_ = a00_[c >> 1], u01_ = a01_[c >> 1];             \
            unsigned int u10_ = a10_[c >> 1], u11_ = a11_[c >> 1];             \
            int sh_ = (c & 1) * 16;                                            \
            float f00_ = bf2f((u16)(u00_ >> sh_)), f01_ = bf2f((u16)(u01_ >> sh_)); \
            float f10_ = bf2f((u16)(u10_ >> sh_)), f11_ = bf2f((u16)(u11_ >> sh_)); \
            r_[c] = w00[st] * f00_ + w01[st] * f01_ + w10[st] * f10_ + w11[st] * f11_; \
        }                                                                      \
        uint4 bu_;                                                             \
        bu_.x = pack2(r_[0], r_[1]); bu_.y = pack2(r_[2], r_[3]);              \
        bu_.z = pack2(r_[4], r_[5]); bu_.w = pack2(r_[6], r_[7]);              \
        bf16x8 bfrag_ = __builtin_bit_cast(bf16x8, bu_);                       \
        const int kcol_ = (cs) * 32 + kq * 8;                                  \
        bf16x8 a0_ = ld8(lw + (size_t)(0 * 16 + n0) * 584 + kcol_);            \
        bf16x8 a1_ = ld8(lw + (size_t)(1 * 16 + n0) * 584 + kcol_);            \
        bf16x8 a2_ = ld8(lw + (size_t)(2 * 16 + n0) * 584 + kcol_);            \
        bf16x8 a3_ = ld8(lw + (size_t)(3 * 16 + n0) * 584 + kcol_);            \
        acc[0] = __builtin_amdgcn_mfma_f32_16x16x32_bf16(a0_, bfrag_, acc[0], 0, 0, 0); \
        acc[1] = __builtin_amdgcn_mfma_f32_16x16x32_bf16(a1_, bfrag_, acc[1], 0, 0, 0); \
        acc[2] = __builtin_amdgcn_mfma_f32_16x16x32_bf16(a2_, bfrag_, acc[2], 0, 0, 0); \
        acc[3] = __builtin_amdgcn_mfma_f32_16x16x32_bf16(a3_, bfrag_, acc[3], 0, 0, 0); \
    }

    DCN_GL(0, 0)
    DCN_GL(1, 1)
#pragma unroll
    for (int cs = 0; cs < 18; cs += 2) {
        DCN_GU(cs, 0)
        if (cs + 2 < 18) DCN_GL(cs + 2, 0)
        DCN_GU(cs + 1, 1)
        if (cs + 3 < 18) DCN_GL(cs + 3, 1)
    }
#undef DCN_GL
#undef DCN_GU

    // epilogue: fea -> NHWC128-pad ch0..63
#pragma unroll
    for (int mt = 0; mt < 4; ++mt) {
        const int mbase = mt * 16 + kq * 4;
        float v0 = acc[mt][0] + bias[mbase];
        float v1 = acc[mt][1] + bias[mbase + 1];
        float v2 = acc[mt][2] + bias[mbase + 2];
        float v3 = acc[mt][3] + bias[mbase + 3];
        size_t off = ((size_t)b * 16900 + (size_t)(y + 1) * 130 + (xx + 1)) * 128 + mbase;
        uint2 u;
        u.x = pack2(v0, v1); u.y = pack2(v2, v3);
        *reinterpret_cast<uint2*>(outN + off) = u;
    }
}

// ---------------- workspace layout (bytes) ----------------------------------
#define T1_OFF 0u            /* NHWC128-pad x||y                 8,652,800 */
#define T3_OFF 8652800u      /* NHWC128-pad off1||upPrev         8,652,800 */
#define T9_OFF 17305600u     /* NHWC128-pad fea||upFea           8,652,800 */
#define T4_OFF 25958400u     /* NHWC64-pad off2                  4,326,400 */
#define T5_OFF 30284800u     /* NHWC64-pad off                   4,326,400 */
#define T6_OFF 34611200u     /* co bf16 NCHW [2][216][16384]    14,155,776 */
#define W1_OFF 48766976u
#define W2_OFF 48914432u
#define W3_OFF 49061888u
#define WF_OFF 49135616u
#define WO_OFF 49283072u     /* padded to 256 rows: 294,912 B */
#define WD_OFF 49577984u     /* ends 49,651,712 */

extern "C" void kernel_launch(void* const* d_in, const int* in_sizes, int n_in,
                              void* d_out, int out_size, void* d_ws, size_t ws_size,
                              hipStream_t stream) {
    const float* x        = (const float*)d_in[0];
    const float* y        = (const float*)d_in[1];
    const float* prev_off = (const float*)d_in[2];
    const float* prev_fea = (const float*)d_in[3];
    const float* w1 = (const float*)d_in[4];  const float* b1 = (const float*)d_in[5];
    const float* w2 = (const float*)d_in[6];  const float* b2 = (const float*)d_in[7];
    const float* w3 = (const float*)d_in[8];  const float* b3 = (const float*)d_in[9];
    const float* w_off = (const float*)d_in[10]; const float* b_off = (const float*)d_in[11];
    const float* w_dcn = (const float*)d_in[12]; const float* b_dcn = (const float*)d_in[13];
    const float* w_fea = (const float*)d_in[14]; const float* b_fea = (const float*)d_in[15];

    float* out_off = (float*)d_out;
    float* out_out = (float*)d_out + (size_t)2 * 64 * 16384;

    char* ws = (char*)d_ws;
    u16* T1 = (u16*)(ws + T1_OFF);
    u16* T3 = (u16*)(ws + T3_OFF);
    u16* T9 = (u16*)(ws + T9_OFF);
    u16* T4 = (u16*)(ws + T4_OFF);
    u16* T5 = (u16*)(ws + T5_OFF);
    u16* T6 = (u16*)(ws + T6_OFF);
    u16* wq1 = (u16*)(ws + W1_OFF);
    u16* wq2 = (u16*)(ws + W2_OFF);
    u16* wq3 = (u16*)(ws + W3_OFF);
    u16* wqf = (u16*)(ws + WF_OFF);
    u16* wqo = (u16*)(ws + WO_OFF);
    u16* wqd = (u16*)(ws + WD_OFF);
    // (wqo pad rows 216..255 never written: consumer stores masked mbase<Cout;
    //  poison bf16 is finite — deterministic, cannot leak)

    // 1. all independent preprocessing in ONE dispatch (long-pole units split 8x)
    preproc<<<dim3(4457), dim3(256), 0, stream>>>(
        x, y, prev_off, prev_fea, w1, w2, w3, w_off, w_dcn, w_fea,
        T1, T3, T9, T4, wq1, wq2, wq3, wqo, wqd, wqf);

    // 2. conv1: concat(x,y) -> off1 (T3 ch0..63)   [512 blocks, 2px x 2K waves]
    conv_tile<128, 4, 2, 1, true, true, 0><<<dim3(512, 1), dim3(256), 0, stream>>>(
        T1, wq1, b1, T3, 0, 128, nullptr, 64);
    // 3. conv2: concat(off1, upPrev*2) -> off2 (T4)
    conv_tile<128, 4, 2, 1, true, true, 0><<<dim3(512, 1), dim3(256), 0, stream>>>(
        T3, wq2, b2, T4, 0, 64, nullptr, 64);
    // 4. conv3: off2 -> off (T5 + output0 NCHW fp32)  [full-K waves, no reduce]
    conv_tile<64, 2, 1, 1, true, true, 1><<<dim3(512, 1), dim3(128), 0, stream>>>(
        T4, wq3, b3, T5, 0, 64, out_off, 64);
    // 5. conv_off: off -> co NCHW bf16, sigmoid on ch>=144
    conv_tile<64, 2, 1, 2, false, false, 2><<<dim3(512, 4), dim3(128), 0, stream>>>(
        T5, wqo, b_off, nullptr, 0, 0, T6, 216);
    // 6. fused DCN: sample + K=576 GEMM -> fea (T9 ch0..63)
    dcn_fused<<<dim3(512), dim3(256), 0, stream>>>(T1, T6, wqd, b_dcn, T9);
    // 7. final conv: concat(fea, upFea) -> output1 NCHW fp32
    conv_tile<128, 4, 2, 1, false, false, 1><<<dim3(512, 1), dim3(256), 0, stream>>>(
        T9, wqf, b_fea, nullptr, 0, 0, out_out, 64);
}

// Round 15
// 135.027 us; speedup vs baseline: 1.1129x; 1.0098x over previous
//
#include <hip/hip_runtime.h>
#include <math.h>

typedef __bf16 bf16x8 __attribute__((ext_vector_type(8)));
typedef float f32x4 __attribute__((ext_vector_type(4)));
typedef unsigned short u16;
typedef __attribute__((address_space(3))) unsigned int lds_u32;
typedef const __attribute__((address_space(1))) unsigned int glb_u32;

// ---------------- helpers ----------------
__device__ __forceinline__ u16 f2bf(float f) {
    unsigned int u = __builtin_bit_cast(unsigned int, f);
    unsigned int r = (u + 0x7FFFu + ((u >> 16) & 1u)) >> 16;   // RNE
    return (u16)r;
}
__device__ __forceinline__ float bf2f(u16 u) {
    unsigned int v = ((unsigned int)u) << 16;
    return __builtin_bit_cast(float, v);
}
__device__ __forceinline__ unsigned int pack2(float a, float b) {
    return (unsigned int)f2bf(a) | ((unsigned int)f2bf(b) << 16);
}
__device__ __forceinline__ bf16x8 ld8(const u16* p) {
    uint4 u = *reinterpret_cast<const uint4*>(p);
    return __builtin_bit_cast(bf16x8, u);
}
__device__ __forceinline__ void gload_lds16(const u16* g, u16* l) {
#if __has_builtin(__builtin_amdgcn_global_load_lds)
    __builtin_amdgcn_global_load_lds((glb_u32*)g, (lds_u32*)l, 16, 0, 0);
#else
    *reinterpret_cast<uint4*>(l) = *reinterpret_cast<const uint4*>(g);
#endif
}

// ---------------- preproc device pieces ----------------
__device__ __forceinline__ void dev_zero(u16* base, int nimg, int C, int B, int tid) {
    int idx = B * 256 + tid;
    int c8 = C >> 3;
    int tot = nimg * 516 * c8;
    if (idx >= tot) return;
    int cb = idx % c8;
    int t = idx / c8;
    int pb = t % 516;
    int img = t / 516;
    int y, x;
    if (pb < 130)      { y = 0;        x = pb; }
    else if (pb < 260) { y = 129;      x = pb - 130; }
    else if (pb < 388) { y = pb - 259; x = 0; }
    else               { y = pb - 387; x = 129; }
    u16* d = base + ((size_t)img * 16900 + (size_t)y * 130 + x) * C + cb * 8;
    uint4 z = {0u, 0u, 0u, 0u};
    *reinterpret_cast<uint4*>(d) = z;
}

// mode 0: dst[o*9*Cin + kk*Cin + ci]; mode 1: dst[o*576 + (ci>>3)*72 + kk*8 + (ci&7)]
__device__ __forceinline__ void dev_repack(const float* w, u16* dst,
                                           int Cout, int Cin, int mode, int B, int tid) {
    int idx = B * 256 + tid;
    int total = Cout * Cin * 9;
    if (idx >= total) return;
    int kk = idx % 9;
    int t = idx / 9;
    int ci = t % Cin;
    int o = t / Cin;
    u16 v = f2bf(w[idx]);
    size_t d;
    if (mode == 0) d = (size_t)o * (9 * Cin) + kk * Cin + ci;
    else           d = (size_t)o * 576 + (ci >> 3) * 72 + kk * 8 + (ci & 7);
    dst[d] = v;
}

// NCHW->NHWC: 4 px x 8 ch per thread; 256 blocks per tensor.
__device__ __forceinline__ void dev_to_nhwc8(const float* src, u16* dst,
                                             int c0, int Ctot, int B, int tid) {
    int b = B >> 7;
    int rem = B & 127;
    int q = rem >> 4;
    int p0 = ((rem & 15) * 256 + tid) * 4;        // pixel base, 4 consecutive
    int y = p0 >> 7, x = p0 & 127;
    const float* s = src + ((size_t)b * 64 + q * 8) * 16384 + p0;
    u16* dbase = dst + (((size_t)b * 16900) + (size_t)(y + 1) * 130 + (x + 1)) * Ctot
                 + c0 + q * 8;
    float4 f[8];
#pragma unroll
    for (int c = 0; c < 8; ++c)
        f[c] = *reinterpret_cast<const float4*>(s + (size_t)c * 16384);
    const float* fp = (const float*)f;
#pragma unroll
    for (int j = 0; j < 4; ++j) {
        uint4 u;
        u.x = pack2(fp[0 * 4 + j], fp[1 * 4 + j]);
        u.y = pack2(fp[2 * 4 + j], fp[3 * 4 + j]);
        u.z = pack2(fp[4 * 4 + j], fp[5 * 4 + j]);
        u.w = pack2(fp[6 * 4 + j], fp[7 * 4 + j]);
        *reinterpret_cast<uint4*>(dbase + (size_t)j * Ctot) = u;
    }
}

// bilinear up2: 1 px x 8 ch per thread; 1024 blocks per tensor.
__device__ __forceinline__ void dev_up2_8(const float* src, u16* dst,
                                          int c0, int Ctot, float scale, int B, int tid) {
    int b = B >> 9;
    int rem = B & 511;
    int q = rem >> 6;
    int pix = (rem & 63) * 256 + tid;
    int y = pix >> 7, x = pix & 127;
    const float f = 63.0f / 127.0f;
    float cy = y * f, cx = x * f;
    float y0f = floorf(cy), x0f = floorf(cx);
    int y0 = (int)y0f, x0 = (int)x0f;
    int y1 = min(y0 + 1, 63), x1 = min(x0 + 1, 63);
    float fy = cy - y0f, fx = cx - x0f;
    float w00 = (1.f - fy) * (1.f - fx) * scale, w01 = (1.f - fy) * fx * scale;
    float w10 = fy * (1.f - fx) * scale, w11 = fy * fx * scale;
    int i00 = y0 * 64 + x0, i01 = y0 * 64 + x1, i10 = y1 * 64 + x0, i11 = y1 * 64 + x1;
    const float* s = src + ((size_t)b * 64 + q * 8) * 4096;
    float v[8];
#pragma unroll
    for (int c = 0; c < 8; ++c) {
        const float* p = s + (size_t)c * 4096;
        v[c] = w00 * p[i00] + w01 * p[i01] + w10 * p[i10] + w11 * p[i11];
    }
    uint4 u;
    u.x = pack2(v[0], v[1]); u.y = pack2(v[2], v[3]);
    u.z = pack2(v[4], v[5]); u.w = pack2(v[6], v[7]);
    u16* d = dst + (((size_t)b * 16900) + (size_t)(y + 1) * 130 + (x + 1)) * Ctot
             + c0 + q * 8;
    *reinterpret_cast<uint4*>(d) = u;
}

// ---------------- one fused preprocessing dispatch (4457 blocks) ------------
__global__ __launch_bounds__(256) void preproc(
    const float* __restrict__ x, const float* __restrict__ y,
    const float* __restrict__ prev_off, const float* __restrict__ prev_fea,
    const float* __restrict__ w1, const float* __restrict__ w2,
    const float* __restrict__ w3, const float* __restrict__ w_off,
    const float* __restrict__ w_dcn, const float* __restrict__ w_fea,
    u16* __restrict__ T1, u16* __restrict__ T3, u16* __restrict__ T9,
    u16* __restrict__ T4,
    u16* __restrict__ wq1, u16* __restrict__ wq2, u16* __restrict__ wq3,
    u16* __restrict__ wqo, u16* __restrict__ wqd, u16* __restrict__ wqf) {
    int B = blockIdx.x, tid = threadIdx.x;
    if (B < 1024) { dev_up2_8(prev_off, T3, 64, 128, 2.0f, B, tid); return; } B -= 1024;
    if (B < 1024) { dev_up2_8(prev_fea, T9, 64, 128, 1.0f, B, tid); return; } B -= 1024;
    if (B < 256) { dev_to_nhwc8(x, T1, 0, 128, B, tid); return; }       B -= 256;
    if (B < 256) { dev_to_nhwc8(y, T1, 64, 128, B, tid); return; }      B -= 256;
    if (B < 129) { dev_zero(T1, 4, 128, B, tid); return; }  B -= 129;   // T1+T3
    if (B < 65)  { dev_zero(T9, 2, 128, B, tid); return; }  B -= 65;
    if (B < 65)  { dev_zero(T4, 4, 64, B, tid); return; }   B -= 65;    // T4+T5
    if (B < 288) { dev_repack(w1, wq1, 64, 128, 0, B, tid); return; }   B -= 288;
    if (B < 288) { dev_repack(w2, wq2, 64, 128, 0, B, tid); return; }   B -= 288;
    if (B < 144) { dev_repack(w3, wq3, 64, 64, 0, B, tid); return; }    B -= 144;
    if (B < 486) { dev_repack(w_off, wqo, 216, 64, 0, B, tid); return; } B -= 486;
    if (B < 144) { dev_repack(w_dcn, wqd, 64, 64, 1, B, tid); return; } B -= 144;
    dev_repack(w_fea, wqf, 64, 128, 0, B, tid);
}

// ---------------- LDS-staged implicit-GEMM conv via MFMA (R11-proven) -------
// Wave decomposition: WAVES = PXW px-columns x KSPLIT K-slices.
// NCHW_MODE: 0 none, 1 fp32, 2 bf16
template<int CIN, int WAVES, int KSPLIT, int ACTM, bool NHWC_OUT, bool OUT_PAD, int NCHW_MODE>
__global__ __launch_bounds__(WAVES * 64) void conv_tile(
    const u16* __restrict__ in, const u16* __restrict__ wgt,
    const float* __restrict__ bias,
    u16* __restrict__ outN, int c0, int Ctot,
    void* __restrict__ outC, int Cout) {
    constexpr int T = WAVES * 64;
    constexpr int PXW = WAVES / KSPLIT;          // px-columns per block
    constexpr int BPR = 4 / PXW;                 // blocks per image row
    constexpr int KCH = CIN / KSPLIT;            // channels per wave
    constexpr int CSTEPS = KCH / 32;             // k-steps per shift per wave
    constexpr int MSK = (CIN == 128) ? 15 : 7;   // 16B-slots per row - 1
    constexpr int RSH = (CIN == 128) ? 8 : 7;    // log2(row bytes)
    __shared__ __align__(16) u16 As[2][64 * CIN];

    const int tid = threadIdx.x;
    const int lane = tid & 63;
    const int wv = tid >> 6;
    const int kslice = wv % KSPLIT;
    const int pxc = wv / KSPLIT;
    const int gx = blockIdx.x;
    const int xh = gx % BPR;
    const int y = (gx / BPR) & 127;
    const int b = gx / (BPR * 128);
    const int mblk = blockIdx.y << 6;
    const int n0 = lane & 15;
    const int kq = lane >> 4;
    const int xbase = xh * (PXW * 32) + pxc * 32;

    const u16* inB = in + (size_t)b * 16900 * CIN;

#define STAGE(ss, bf) {                                                        \
        _Pragma("unroll")                                                      \
        for (int i_ = 0; i_ < (8 * CIN) / T; ++i_) {                           \
            int L_ = (i_ * T + tid) * 16;                                      \
            int row_ = L_ >> RSH;                                              \
            int c16_ = (L_ >> 4) & MSK;                                        \
            int sc_ = c16_ ^ (row_ & MSK);                                     \
            const u16* src_ = wgt + (size_t)(mblk + row_) * (9 * CIN)          \
                              + (ss) * CIN + sc_ * 8;                          \
            gload_lds16(src_, &As[bf][L_ >> 1]);                               \
        }                                                                      \
    }

    f32x4 acc[4][2] = {};

    STAGE(0, 0)
    __syncthreads();

    for (int s = 0; s < 9; ++s) {
        const int buf = s & 1;
        if (s < 8) STAGE(s + 1, buf ^ 1)

        const int dy = s / 3, dx = s - dy * 3;
        const u16* brow = inB + ((size_t)(y + dy) * 130 + (xbase + n0 + dx)) * CIN
                          + kq * 8;
        const u16* ab = &As[buf][0];
#pragma unroll
        for (int c = 0; c < CSTEPS; ++c) {
            const int kch = kslice * KCH + c * 32;
            bf16x8 b0 = ld8(brow + kch);
            bf16x8 b1 = ld8(brow + 16 * CIN + kch);
            const int colb = (((kch >> 3) + kq) ^ (n0 & MSK)) * 8;
            bf16x8 a0 = ld8(ab + (0 * 16 + n0) * CIN + colb);
            bf16x8 a1 = ld8(ab + (1 * 16 + n0) * CIN + colb);
            bf16x8 a2 = ld8(ab + (2 * 16 + n0) * CIN + colb);
            bf16x8 a3 = ld8(ab + (3 * 16 + n0) * CIN + colb);
            acc[0][0] = __builtin_amdgcn_mfma_f32_16x16x32_bf16(a0, b0, acc[0][0], 0, 0, 0);
            acc[0][1] = __builtin_amdgcn_mfma_f32_16x16x32_bf16(a0, b1, acc[0][1], 0, 0, 0);
            acc[1][0] = __builtin_amdgcn_mfma_f32_16x16x32_bf16(a1, b0, acc[1][0], 0, 0, 0);
            acc[1][1] = __builtin_amdgcn_mfma_f32_16x16x32_bf16(a1, b1, acc[1][1], 0, 0, 0);
            acc[2][0] = __builtin_amdgcn_mfma_f32_16x16x32_bf16(a2, b0, acc[2][0], 0, 0, 0);
            acc[2][1] = __builtin_amdgcn_mfma_f32_16x16x32_bf16(a2, b1, acc[2][1], 0, 0, 0);
            acc[3][0] = __builtin_amdgcn_mfma_f32_16x16x32_bf16(a3, b0, acc[3][0], 0, 0, 0);
            acc[3][1] = __builtin_amdgcn_mfma_f32_16x16x32_bf16(a3, b1, acc[3][1], 0, 0, 0);
        }
        __syncthreads();
    }
#undef STAGE

    // 2-way K reduce (kslice 1 -> kslice 0) when split
    if (KSPLIT == 2) {
        float* red = (float*)(&As[0][0]);
        if (kslice == 1) {
#pragma unroll
            for (int mt = 0; mt < 4; ++mt)
#pragma unroll
                for (int nt = 0; nt < 2; ++nt)
                    *reinterpret_cast<f32x4*>(
                        &red[((pxc * 8) + mt * 2 + nt) * 256 + lane * 4]) = acc[mt][nt];
        }
        __syncthreads();
        if (kslice == 1) return;
#pragma unroll
        for (int mt = 0; mt < 4; ++mt)
#pragma unroll
            for (int nt = 0; nt < 2; ++nt)
                acc[mt][nt] += *reinterpret_cast<const f32x4*>(
                    &red[((pxc * 8) + mt * 2 + nt) * 256 + lane * 4]);
    }

    // epilogue: each surviving wave stores its own 32-px column, all 4 m-tiles
#pragma unroll
    for (int mt = 0; mt < 4; ++mt) {
        const int mbase = mblk + mt * 16 + kq * 4;
        float bs0 = 0.f, bs1 = 0.f, bs2 = 0.f, bs3 = 0.f;
        if (mbase < Cout) {
            bs0 = bias[mbase]; bs1 = bias[mbase + 1];
            bs2 = bias[mbase + 2]; bs3 = bias[mbase + 3];
        }
#pragma unroll
        for (int nt = 0; nt < 2; ++nt) {
            const int xx = xbase + nt * 16 + n0;
            float v0 = acc[mt][nt][0] + bs0, v1 = acc[mt][nt][1] + bs1;
            float v2 = acc[mt][nt][2] + bs2, v3 = acc[mt][nt][3] + bs3;
            if (ACTM == 1) {
                v0 = (v0 >= 0.f) ? v0 : 0.1f * v0;
                v1 = (v1 >= 0.f) ? v1 : 0.1f * v1;
                v2 = (v2 >= 0.f) ? v2 : 0.1f * v2;
                v3 = (v3 >= 0.f) ? v3 : 0.1f * v3;
            } else if (ACTM == 2) {
                if (mbase >= 144) {
                    v0 = 1.f / (1.f + expf(-v0));
                    v1 = 1.f / (1.f + expf(-v1));
                    v2 = 1.f / (1.f + expf(-v2));
                    v3 = 1.f / (1.f + expf(-v3));
                }
            }
            if (NHWC_OUT && mbase < Cout) {
                size_t pix = OUT_PAD ? ((size_t)(y + 1) * 130 + xx + 1)
                                     : ((size_t)y * 128 + xx);
                size_t off = ((size_t)b * (OUT_PAD ? 16900 : 16384) + pix) * Ctot + c0 + mbase;
                uint2 u;
                u.x = pack2(v0, v1); u.y = pack2(v2, v3);
                *reinterpret_cast<uint2*>(outN + off) = u;
            }
            if (NCHW_MODE == 1 && mbase < Cout) {
                float* oc = (float*)outC;
                size_t o = ((size_t)(b * Cout + mbase)) * 16384 + (size_t)y * 128 + xx;
                oc[o] = v0; oc[o + 16384] = v1;
                oc[o + 2 * 16384] = v2; oc[o + 3 * 16384] = v3;
            }
            if (NCHW_MODE == 2 && mbase < Cout) {
                u16* oc = (u16*)outC;
                size_t o = ((size_t)(b * Cout + mbase)) * 16384 + (size_t)y * 128 + xx;
                oc[o] = f2bf(v0); oc[o + 16384] = f2bf(v1);
                oc[o + 2 * 16384] = f2bf(v2); oc[o + 3 * 16384] = f2bf(v3);
            }
        }
    }
}

// ---------------- fused DCNv2: sample in-register + K=576 MFMA GEMM ---------
// xn : NHWC128-pad bf16 (x at ch 0..63)
// co : NCHW bf16 [b][216][16384]; ch>=144 already sigmoided
// wgt: bf16 [64][576] in sample order (g*72 + kk*8 + c)
__global__ __launch_bounds__(256, 2) void dcn_fused(
    const u16* __restrict__ xn, const u16* __restrict__ co,
    const u16* __restrict__ wgt, const float* __restrict__ bias,
    u16* __restrict__ outN) {
    __shared__ u16 lw[64 * 584];      // padded stride 584 (bank-spread)
    {
        int t = threadIdx.x;
        int o = t >> 2, chunk = t & 3;
        const u16* src = wgt + o * 576 + chunk * 144;
        u16* dst = lw + o * 584 + chunk * 144;
#pragma unroll
        for (int i = 0; i < 18; ++i)
            *reinterpret_cast<uint4*>(dst + i * 8) =
                *reinterpret_cast<const uint4*>(src + i * 8);
    }
    __syncthreads();

    const int lane = threadIdx.x & 63;
    const int wv = threadIdx.x >> 6;
    const int half = blockIdx.x & 1;
    const int y = (blockIdx.x >> 1) & 127;
    const int b = blockIdx.x >> 8;
    const int n0 = lane & 15;
    const int kq = lane >> 4;
    const int xx = half * 64 + wv * 16 + n0;
    const int p = y * 128 + xx;

    const u16* cob = co + (size_t)b * 216 * 16384 + p;
    const u16* xb = xn + (size_t)b * 16900 * 128;

    float offy[18], offx[18], mvv[18];
#pragma unroll
    for (int cs = 0; cs < 18; ++cs) {
        int gk8 = cs * 4 + kq;
        offy[cs] = bf2f(cob[(size_t)gk8 * 16384]);
        offx[cs] = bf2f(cob[(size_t)(72 + gk8) * 16384]);
        mvv[cs]  = bf2f(cob[(size_t)(144 + gk8) * 16384]);   // pre-sigmoided
    }

    f32x4 acc[4] = {};
    float w00[2], w01[2], w10[2], w11[2];
    uint4 q00[2], q01[2], q10[2], q11[2];

#define DCN_GL(cs, st) {                                                       \
        int gk8_ = (cs) * 4 + kq;                                              \
        int g_ = (gk8_ * 57) >> 9;                                             \
        int kk_ = gk8_ - 9 * g_;                                               \
        int ky_ = (kk_ * 11) >> 5;                                             \
        int kx_ = kk_ - 3 * ky_;                                               \
        float py_ = offy[cs] + (float)(ky_ - 1) + (float)y;                    \
        float px_ = offx[cs] + (float)(kx_ - 1) + (float)xx;                   \
        float y0f_ = floorf(py_), x0f_ = floorf(px_);                          \
        float wy_ = py_ - y0f_, wx_ = px_ - x0f_;                              \
        int y0_ = (int)y0f_, x0_ = (int)x0f_, y1_ = y0_ + 1, x1_ = x0_ + 1;    \
        float m00_ = ((unsigned)y0_ < 128u && (unsigned)x0_ < 128u) ? 1.f : 0.f; \
        float m01_ = ((unsigned)y0_ < 128u && (unsigned)x1_ < 128u) ? 1.f : 0.f; \
        float m10_ = ((unsigned)y1_ < 128u && (unsigned)x0_ < 128u) ? 1.f : 0.f; \
        float m11_ = ((unsigned)y1_ < 128u && (unsigned)x1_ < 128u) ? 1.f : 0.f; \
        float mv_ = mvv[cs];                                                   \
        w00[st] = (1.f - wy_) * (1.f - wx_) * m00_ * mv_;                      \
        w01[st] = (1.f - wy_) * wx_ * m01_ * mv_;                              \
        w10[st] = wy_ * (1.f - wx_) * m10_ * mv_;                              \
        w11[st] = wy_ * wx_ * m11_ * mv_;                                      \
        int y0c_ = min(max(y0_, 0), 127), y1c_ = min(max(y1_, 0), 127);        \
        int x0c_ = min(max(x0_, 0), 127), x1c_ = min(max(x1_, 0), 127);        \
        const u16* xg_ = xb + g_ * 8;                                          \
        q00[st] = *reinterpret_cast<const uint4*>(xg_ + ((size_t)(y0c_ + 1) * 130 + x0c_ + 1) * 128); \
        q01[st] = *reinterpret_cast<const uint4*>(xg_ + ((size_t)(y0c_ + 1) * 130 + x1c_ + 1) * 128); \
        q10[st] = *reinterpret_cast<const uint4*>(xg_ + ((size_t)(y1c_ + 1) * 130 + x0c_ + 1) * 128); \
        q11[st] = *reinterpret_cast<const uint4*>(xg_ + ((size_t)(y1c_ + 1) * 130 + x1c_ + 1) * 128); \
    }

#define DCN_GU(cs, st) {                                                       \
        const unsigned int* a00_ = &q00[st].x; const unsigned int* a01_ = &q01[st].x; \
        const unsigned int* a10_ = &q10[st].x; const unsigned int* a11_ = &q11[st].x; \
        float r_[8];                                                           \
        _Pragma("unroll")                                                      \
        for (int c = 0; c < 8; ++c) {                                          \
            unsigned int u00_ = a00_[c >> 1], u01_ = a01_[c >> 1];             \
            unsigned int u10_ = a10_[c >> 1], u11_ = a11_[c >> 1];             \
            int sh_ = (c & 1) * 16;                                            \
            float f00_ = bf2f((u16)(u00_ >> sh_)), f01_ = bf2f((u16)(u01_ >> sh_)); \
            float f10_ = bf2f((u16)(u10_ >> sh_)), f11_ = bf2f((u16)(u11_ >> sh_)); \
            r_[c] = w00[st] * f00_ + w01[st] * f01_ + w10[st] * f10_ + w11[st] * f11_; \
        }                                                                      \
        uint4 bu_;                                                             \
        bu_.x = pack2(r_[0], r_[1]); bu_.y = pack2(r_[2], r_[3]);              \
        bu_.z = pack2(r_[4], r_[5]); bu_.w = pack2(r_[6], r_[7]);              \
        bf16x8 bfrag_ = __builtin_bit_cast(bf16x8, bu_);                       \
        const int kcol_ = (cs) * 32 + kq * 8;                                  \
        bf16x8 a0_ = ld8(lw + (size_t)(0 * 16 + n0) * 584 + kcol_);            \
        bf16x8 a1_ = ld8(lw + (size_t)(1 * 16 + n0) * 584 + kcol_);            \
        bf16x8 a2_ = ld8(lw + (size_t)(2 * 16 + n0) * 584 + kcol_);            \
        bf16x8 a3_ = ld8(lw + (size_t)(3 * 16 + n0) * 584 + kcol_);            \
        acc[0] = __builtin_amdgcn_mfma_f32_16x16x32_bf16(a0_, bfrag_, acc[0], 0, 0, 0); \
        acc[1] = __builtin_amdgcn_mfma_f32_16x16x32_bf16(a1_, bfrag_, acc[1], 0, 0, 0); \
        acc[2] = __builtin_amdgcn_mfma_f32_16x16x32_bf16(a2_, bfrag_, acc[2], 0, 0, 0); \
        acc[3] = __builtin_amdgcn_mfma_f32_16x16x32_bf16(a3_, bfrag_, acc[3], 0, 0, 0); \
    }

    DCN_GL(0, 0)
    DCN_GL(1, 1)
#pragma unroll
    for (int cs = 0; cs < 18; cs += 2) {
        DCN_GU(cs, 0)
        if (cs + 2 < 18) DCN_GL(cs + 2, 0)
        DCN_GU(cs + 1, 1)
        if (cs + 3 < 18) DCN_GL(cs + 3, 1)
    }
#undef DCN_GL
#undef DCN_GU

    // epilogue: fea -> NHWC128-pad ch0..63
#pragma unroll
    for (int mt = 0; mt < 4; ++mt) {
        const int mbase = mt * 16 + kq * 4;
        float v0 = acc[mt][0] + bias[mbase];
        float v1 = acc[mt][1] + bias[mbase + 1];
        float v2 = acc[mt][2] + bias[mbase + 2];
        float v3 = acc[mt][3] + bias[mbase + 3];
        size_t off = ((size_t)b * 16900 + (size_t)(y + 1) * 130 + (xx + 1)) * 128 + mbase;
        uint2 u;
        u.x = pack2(v0, v1); u.y = pack2(v2, v3);
        *reinterpret_cast<uint2*>(outN + off) = u;
    }
}

// ---------------- workspace layout (bytes) ----------------------------------
#define T1_OFF 0u            /* NHWC128-pad x||y                 8,652,800 */
#define T3_OFF 8652800u      /* NHWC128-pad off1||upPrev         8,652,800 */
#define T9_OFF 17305600u     /* NHWC128-pad fea||upFea           8,652,800 */
#define T4_OFF 25958400u     /* NHWC64-pad off2                  4,326,400 */
#define T5_OFF 30284800u     /* NHWC64-pad off                   4,326,400 */
#define T6_OFF 34611200u     /* co bf16 NCHW [2][216][16384]    14,155,776 */
#define W1_OFF 48766976u
#define W2_OFF 48914432u
#define W3_OFF 49061888u
#define WF_OFF 49135616u
#define WO_OFF 49283072u     /* padded to 256 rows: 294,912 B */
#define WD_OFF 49577984u     /* ends 49,651,712 */

extern "C" void kernel_launch(void* const* d_in, const int* in_sizes, int n_in,
                              void* d_out, int out_size, void* d_ws, size_t ws_size,
                              hipStream_t stream) {
    const float* x        = (const float*)d_in[0];
    const float* y        = (const float*)d_in[1];
    const float* prev_off = (const float*)d_in[2];
    const float* prev_fea = (const float*)d_in[3];
    const float* w1 = (const float*)d_in[4];  const float* b1 = (const float*)d_in[5];
    const float* w2 = (const float*)d_in[6];  const float* b2 = (const float*)d_in[7];
    const float* w3 = (const float*)d_in[8];  const float* b3 = (const float*)d_in[9];
    const float* w_off = (const float*)d_in[10]; const float* b_off = (const float*)d_in[11];
    const float* w_dcn = (const float*)d_in[12]; const float* b_dcn = (const float*)d_in[13];
    const float* w_fea = (const float*)d_in[14]; const float* b_fea = (const float*)d_in[15];

    float* out_off = (float*)d_out;
    float* out_out = (float*)d_out + (size_t)2 * 64 * 16384;

    char* ws = (char*)d_ws;
    u16* T1 = (u16*)(ws + T1_OFF);
    u16* T3 = (u16*)(ws + T3_OFF);
    u16* T9 = (u16*)(ws + T9_OFF);
    u16* T4 = (u16*)(ws + T4_OFF);
    u16* T5 = (u16*)(ws + T5_OFF);
    u16* T6 = (u16*)(ws + T6_OFF);
    u16* wq1 = (u16*)(ws + W1_OFF);
    u16* wq2 = (u16*)(ws + W2_OFF);
    u16* wq3 = (u16*)(ws + W3_OFF);
    u16* wqf = (u16*)(ws + WF_OFF);
    u16* wqo = (u16*)(ws + WO_OFF);
    u16* wqd = (u16*)(ws + WD_OFF);
    // (wqo pad rows 216..255 never written: consumer stores masked mbase<Cout;
    //  poison bf16 is finite — deterministic, cannot leak)

    // 1. all independent preprocessing in ONE dispatch (long-pole units split 8x)
    preproc<<<dim3(4457), dim3(256), 0, stream>>>(
        x, y, prev_off, prev_fea, w1, w2, w3, w_off, w_dcn, w_fea,
        T1, T3, T9, T4, wq1, wq2, wq3, wqo, wqd, wqf);

    // 2. conv1: concat(x,y) -> off1 (T3 ch0..63)   [512 blocks, 2px x 2K waves]
    conv_tile<128, 4, 2, 1, true, true, 0><<<dim3(512, 1), dim3(256), 0, stream>>>(
        T1, wq1, b1, T3, 0, 128, nullptr, 64);
    // 3. conv2: concat(off1, upPrev*2) -> off2 (T4)
    conv_tile<128, 4, 2, 1, true, true, 0><<<dim3(512, 1), dim3(256), 0, stream>>>(
        T3, wq2, b2, T4, 0, 64, nullptr, 64);
    // 4. conv3: off2 -> off (T5 + output0 NCHW fp32)  [4px-wave blocks, 256 blocks]
    conv_tile<64, 4, 1, 1, true, true, 1><<<dim3(256, 1), dim3(256), 0, stream>>>(
        T4, wq3, b3, T5, 0, 64, out_off, 64);
    // 5. conv_off: off -> co NCHW bf16, sigmoid on ch>=144  [4px-wave blocks]
    conv_tile<64, 4, 1, 2, false, false, 2><<<dim3(256, 4), dim3(256), 0, stream>>>(
        T5, wqo, b_off, nullptr, 0, 0, T6, 216);
    // 6. fused DCN: sample + K=576 GEMM -> fea (T9 ch0..63)
    dcn_fused<<<dim3(512), dim3(256), 0, stream>>>(T1, T6, wqd, b_dcn, T9);
    // 7. final conv: concat(fea, upFea) -> output1 NCHW fp32
    conv_tile<128, 4, 2, 1, false, false, 1><<<dim3(512, 1), dim3(256), 0, stream>>>(
        T9, wqf, b_fea, nullptr, 0, 0, out_out, 64);
}

// Round 16
// 131.999 us; speedup vs baseline: 1.1384x; 1.0229x over previous
//
#include <hip/hip_runtime.h>
#include <math.h>

typedef __bf16 bf16x8 __attribute__((ext_vector_type(8)));
typedef float f32x4 __attribute__((ext_vector_type(4)));
typedef unsigned short u16;
typedef __attribute__((address_space(3))) unsigned int lds_u32;
typedef const __attribute__((address_space(1))) unsigned int glb_u32;

// ---------------- helpers ----------------
__device__ __forceinline__ u16 f2bf(float f) {
    unsigned int u = __builtin_bit_cast(unsigned int, f);
    unsigned int r = (u + 0x7FFFu + ((u >> 16) & 1u)) >> 16;   // RNE
    return (u16)r;
}
__device__ __forceinline__ float bf2f(u16 u) {
    unsigned int v = ((unsigned int)u) << 16;
    return __builtin_bit_cast(float, v);
}
__device__ __forceinline__ unsigned int pack2(float a, float b) {
    return (unsigned int)f2bf(a) | ((unsigned int)f2bf(b) << 16);
}
__device__ __forceinline__ bf16x8 ld8(const u16* p) {
    uint4 u = *reinterpret_cast<const uint4*>(p);
    return __builtin_bit_cast(bf16x8, u);
}
__device__ __forceinline__ void gload_lds16(const u16* g, u16* l) {
#if __has_builtin(__builtin_amdgcn_global_load_lds)
    __builtin_amdgcn_global_load_lds((glb_u32*)g, (lds_u32*)l, 16, 0, 0);
#else
    *reinterpret_cast<uint4*>(l) = *reinterpret_cast<const uint4*>(g);
#endif
}

// ---------------- preproc device pieces ----------------
__device__ __forceinline__ void dev_zero(u16* base, int nimg, int C, int B, int tid) {
    int idx = B * 256 + tid;
    int c8 = C >> 3;
    int tot = nimg * 516 * c8;
    if (idx >= tot) return;
    int cb = idx % c8;
    int t = idx / c8;
    int pb = t % 516;
    int img = t / 516;
    int y, x;
    if (pb < 130)      { y = 0;        x = pb; }
    else if (pb < 260) { y = 129;      x = pb - 130; }
    else if (pb < 388) { y = pb - 259; x = 0; }
    else               { y = pb - 387; x = 129; }
    u16* d = base + ((size_t)img * 16900 + (size_t)y * 130 + x) * C + cb * 8;
    uint4 z = {0u, 0u, 0u, 0u};
    *reinterpret_cast<uint4*>(d) = z;
}

// mode 0: dst[o*9*Cin + kk*Cin + ci]; mode 1: dst[o*576 + (ci>>3)*72 + kk*8 + (ci&7)]
__device__ __forceinline__ void dev_repack(const float* w, u16* dst,
                                           int Cout, int Cin, int mode, int B, int tid) {
    int idx = B * 256 + tid;
    int total = Cout * Cin * 9;
    if (idx >= total) return;
    int kk = idx % 9;
    int t = idx / 9;
    int ci = t % Cin;
    int o = t / Cin;
    u16 v = f2bf(w[idx]);
    size_t d;
    if (mode == 0) d = (size_t)o * (9 * Cin) + kk * Cin + ci;
    else           d = (size_t)o * 576 + (ci >> 3) * 72 + kk * 8 + (ci & 7);
    dst[d] = v;
}

// NCHW->NHWC: 4 px x 8 ch per thread; 256 blocks per tensor.
__device__ __forceinline__ void dev_to_nhwc8(const float* src, u16* dst,
                                             int c0, int Ctot, int B, int tid) {
    int b = B >> 7;
    int rem = B & 127;
    int q = rem >> 4;
    int p0 = ((rem & 15) * 256 + tid) * 4;        // pixel base, 4 consecutive
    int y = p0 >> 7, x = p0 & 127;
    const float* s = src + ((size_t)b * 64 + q * 8) * 16384 + p0;
    u16* dbase = dst + (((size_t)b * 16900) + (size_t)(y + 1) * 130 + (x + 1)) * Ctot
                 + c0 + q * 8;
    float4 f[8];
#pragma unroll
    for (int c = 0; c < 8; ++c)
        f[c] = *reinterpret_cast<const float4*>(s + (size_t)c * 16384);
    const float* fp = (const float*)f;
#pragma unroll
    for (int j = 0; j < 4; ++j) {
        uint4 u;
        u.x = pack2(fp[0 * 4 + j], fp[1 * 4 + j]);
        u.y = pack2(fp[2 * 4 + j], fp[3 * 4 + j]);
        u.z = pack2(fp[4 * 4 + j], fp[5 * 4 + j]);
        u.w = pack2(fp[6 * 4 + j], fp[7 * 4 + j]);
        *reinterpret_cast<uint4*>(dbase + (size_t)j * Ctot) = u;
    }
}

// bilinear up2: 1 px x 8 ch per thread; 1024 blocks per tensor.
__device__ __forceinline__ void dev_up2_8(const float* src, u16* dst,
                                          int c0, int Ctot, float scale, int B, int tid) {
    int b = B >> 9;
    int rem = B & 511;
    int q = rem >> 6;
    int pix = (rem & 63) * 256 + tid;
    int y = pix >> 7, x = pix & 127;
    const float f = 63.0f / 127.0f;
    float cy = y * f, cx = x * f;
    float y0f = floorf(cy), x0f = floorf(cx);
    int y0 = (int)y0f, x0 = (int)x0f;
    int y1 = min(y0 + 1, 63), x1 = min(x0 + 1, 63);
    float fy = cy - y0f, fx = cx - x0f;
    float w00 = (1.f - fy) * (1.f - fx) * scale, w01 = (1.f - fy) * fx * scale;
    float w10 = fy * (1.f - fx) * scale, w11 = fy * fx * scale;
    int i00 = y0 * 64 + x0, i01 = y0 * 64 + x1, i10 = y1 * 64 + x0, i11 = y1 * 64 + x1;
    const float* s = src + ((size_t)b * 64 + q * 8) * 4096;
    float v[8];
#pragma unroll
    for (int c = 0; c < 8; ++c) {
        const float* p = s + (size_t)c * 4096;
        v[c] = w00 * p[i00] + w01 * p[i01] + w10 * p[i10] + w11 * p[i11];
    }
    uint4 u;
    u.x = pack2(v[0], v[1]); u.y = pack2(v[2], v[3]);
    u.z = pack2(v[4], v[5]); u.w = pack2(v[6], v[7]);
    u16* d = dst + (((size_t)b * 16900) + (size_t)(y + 1) * 130 + (x + 1)) * Ctot
             + c0 + q * 8;
    *reinterpret_cast<uint4*>(d) = u;
}

// ---------------- one fused preprocessing dispatch (4457 blocks) ------------
__global__ __launch_bounds__(256) void preproc(
    const float* __restrict__ x, const float* __restrict__ y,
    const float* __restrict__ prev_off, const float* __restrict__ prev_fea,
    const float* __restrict__ w1, const float* __restrict__ w2,
    const float* __restrict__ w3, const float* __restrict__ w_off,
    const float* __restrict__ w_dcn, const float* __restrict__ w_fea,
    u16* __restrict__ T1, u16* __restrict__ T3, u16* __restrict__ T9,
    u16* __restrict__ T4,
    u16* __restrict__ wq1, u16* __restrict__ wq2, u16* __restrict__ wq3,
    u16* __restrict__ wqo, u16* __restrict__ wqd, u16* __restrict__ wqf) {
    int B = blockIdx.x, tid = threadIdx.x;
    if (B < 1024) { dev_up2_8(prev_off, T3, 64, 128, 2.0f, B, tid); return; } B -= 1024;
    if (B < 1024) { dev_up2_8(prev_fea, T9, 64, 128, 1.0f, B, tid); return; } B -= 1024;
    if (B < 256) { dev_to_nhwc8(x, T1, 0, 128, B, tid); return; }       B -= 256;
    if (B < 256) { dev_to_nhwc8(y, T1, 64, 128, B, tid); return; }      B -= 256;
    if (B < 129) { dev_zero(T1, 4, 128, B, tid); return; }  B -= 129;   // T1+T3
    if (B < 65)  { dev_zero(T9, 2, 128, B, tid); return; }  B -= 65;
    if (B < 65)  { dev_zero(T4, 4, 64, B, tid); return; }   B -= 65;    // T4+T5
    if (B < 288) { dev_repack(w1, wq1, 64, 128, 0, B, tid); return; }   B -= 288;
    if (B < 288) { dev_repack(w2, wq2, 64, 128, 0, B, tid); return; }   B -= 288;
    if (B < 144) { dev_repack(w3, wq3, 64, 64, 0, B, tid); return; }    B -= 144;
    if (B < 486) { dev_repack(w_off, wqo, 216, 64, 0, B, tid); return; } B -= 486;
    if (B < 144) { dev_repack(w_dcn, wqd, 64, 64, 1, B, tid); return; } B -= 144;
    dev_repack(w_fea, wqf, 64, 128, 0, B, tid);
}

// ---------------- LDS-staged implicit-GEMM conv via MFMA (R11-proven) -------
// Wave decomposition: WAVES = PXW px-columns x KSPLIT K-slices.
// NCHW_MODE: 0 none, 1 fp32, 2 bf16
template<int CIN, int WAVES, int KSPLIT, int ACTM, bool NHWC_OUT, bool OUT_PAD, int NCHW_MODE>
__global__ __launch_bounds__(WAVES * 64) void conv_tile(
    const u16* __restrict__ in, const u16* __restrict__ wgt,
    const float* __restrict__ bias,
    u16* __restrict__ outN, int c0, int Ctot,
    void* __restrict__ outC, int Cout) {
    constexpr int T = WAVES * 64;
    constexpr int PXW = WAVES / KSPLIT;          // px-columns per block
    constexpr int BPR = 4 / PXW;                 // blocks per image row
    constexpr int KCH = CIN / KSPLIT;            // channels per wave
    constexpr int CSTEPS = KCH / 32;             // k-steps per shift per wave
    constexpr int MSK = (CIN == 128) ? 15 : 7;   // 16B-slots per row - 1
    constexpr int RSH = (CIN == 128) ? 8 : 7;    // log2(row bytes)
    __shared__ __align__(16) u16 As[2][64 * CIN];

    const int tid = threadIdx.x;
    const int lane = tid & 63;
    const int wv = tid >> 6;
    const int kslice = wv % KSPLIT;
    const int pxc = wv / KSPLIT;
    const int gx = blockIdx.x;
    const int xh = gx % BPR;
    const int y = (gx / BPR) & 127;
    const int b = gx / (BPR * 128);
    const int mblk = blockIdx.y << 6;
    const int n0 = lane & 15;
    const int kq = lane >> 4;
    const int xbase = xh * (PXW * 32) + pxc * 32;

    const u16* inB = in + (size_t)b * 16900 * CIN;

#define STAGE(ss, bf) {                                                        \
        _Pragma("unroll")                                                      \
        for (int i_ = 0; i_ < (8 * CIN) / T; ++i_) {                           \
            int L_ = (i_ * T + tid) * 16;                                      \
            int row_ = L_ >> RSH;                                              \
            int c16_ = (L_ >> 4) & MSK;                                        \
            int sc_ = c16_ ^ (row_ & MSK);                                     \
            const u16* src_ = wgt + (size_t)(mblk + row_) * (9 * CIN)          \
                              + (ss) * CIN + sc_ * 8;                          \
            gload_lds16(src_, &As[bf][L_ >> 1]);                               \
        }                                                                      \
    }

    f32x4 acc[4][2] = {};

    STAGE(0, 0)
    __syncthreads();

    for (int s = 0; s < 9; ++s) {
        const int buf = s & 1;
        if (s < 8) STAGE(s + 1, buf ^ 1)

        const int dy = s / 3, dx = s - dy * 3;
        const u16* brow = inB + ((size_t)(y + dy) * 130 + (xbase + n0 + dx)) * CIN
                          + kq * 8;
        const u16* ab = &As[buf][0];
#pragma unroll
        for (int c = 0; c < CSTEPS; ++c) {
            const int kch = kslice * KCH + c * 32;
            bf16x8 b0 = ld8(brow + kch);
            bf16x8 b1 = ld8(brow + 16 * CIN + kch);
            const int colb = (((kch >> 3) + kq) ^ (n0 & MSK)) * 8;
            bf16x8 a0 = ld8(ab + (0 * 16 + n0) * CIN + colb);
            bf16x8 a1 = ld8(ab + (1 * 16 + n0) * CIN + colb);
            bf16x8 a2 = ld8(ab + (2 * 16 + n0) * CIN + colb);
            bf16x8 a3 = ld8(ab + (3 * 16 + n0) * CIN + colb);
            acc[0][0] = __builtin_amdgcn_mfma_f32_16x16x32_bf16(a0, b0, acc[0][0], 0, 0, 0);
            acc[0][1] = __builtin_amdgcn_mfma_f32_16x16x32_bf16(a0, b1, acc[0][1], 0, 0, 0);
            acc[1][0] = __builtin_amdgcn_mfma_f32_16x16x32_bf16(a1, b0, acc[1][0], 0, 0, 0);
            acc[1][1] = __builtin_amdgcn_mfma_f32_16x16x32_bf16(a1, b1, acc[1][1], 0, 0, 0);
            acc[2][0] = __builtin_amdgcn_mfma_f32_16x16x32_bf16(a2, b0, acc[2][0], 0, 0, 0);
            acc[2][1] = __builtin_amdgcn_mfma_f32_16x16x32_bf16(a2, b1, acc[2][1], 0, 0, 0);
            acc[3][0] = __builtin_amdgcn_mfma_f32_16x16x32_bf16(a3, b0, acc[3][0], 0, 0, 0);
            acc[3][1] = __builtin_amdgcn_mfma_f32_16x16x32_bf16(a3, b1, acc[3][1], 0, 0, 0);
        }
        __syncthreads();
    }
#undef STAGE

    // 2-way K reduce (kslice 1 -> kslice 0) when split
    if (KSPLIT == 2) {
        float* red = (float*)(&As[0][0]);
        if (kslice == 1) {
#pragma unroll
            for (int mt = 0; mt < 4; ++mt)
#pragma unroll
                for (int nt = 0; nt < 2; ++nt)
                    *reinterpret_cast<f32x4*>(
                        &red[((pxc * 8) + mt * 2 + nt) * 256 + lane * 4]) = acc[mt][nt];
        }
        __syncthreads();
        if (kslice == 1) return;
#pragma unroll
        for (int mt = 0; mt < 4; ++mt)
#pragma unroll
            for (int nt = 0; nt < 2; ++nt)
                acc[mt][nt] += *reinterpret_cast<const f32x4*>(
                    &red[((pxc * 8) + mt * 2 + nt) * 256 + lane * 4]);
    }

    // epilogue: each surviving wave stores its own 32-px column, all 4 m-tiles
#pragma unroll
    for (int mt = 0; mt < 4; ++mt) {
        const int mbase = mblk + mt * 16 + kq * 4;
        float bs0 = 0.f, bs1 = 0.f, bs2 = 0.f, bs3 = 0.f;
        if (mbase < Cout) {
            bs0 = bias[mbase]; bs1 = bias[mbase + 1];
            bs2 = bias[mbase + 2]; bs3 = bias[mbase + 3];
        }
#pragma unroll
        for (int nt = 0; nt < 2; ++nt) {
            const int xx = xbase + nt * 16 + n0;
            float v0 = acc[mt][nt][0] + bs0, v1 = acc[mt][nt][1] + bs1;
            float v2 = acc[mt][nt][2] + bs2, v3 = acc[mt][nt][3] + bs3;
            if (ACTM == 1) {
                v0 = (v0 >= 0.f) ? v0 : 0.1f * v0;
                v1 = (v1 >= 0.f) ? v1 : 0.1f * v1;
                v2 = (v2 >= 0.f) ? v2 : 0.1f * v2;
                v3 = (v3 >= 0.f) ? v3 : 0.1f * v3;
            } else if (ACTM == 2) {
                if (mbase >= 144) {
                    v0 = 1.f / (1.f + expf(-v0));
                    v1 = 1.f / (1.f + expf(-v1));
                    v2 = 1.f / (1.f + expf(-v2));
                    v3 = 1.f / (1.f + expf(-v3));
                }
            }
            if (NHWC_OUT && mbase < Cout) {
                size_t pix = OUT_PAD ? ((size_t)(y + 1) * 130 + xx + 1)
                                     : ((size_t)y * 128 + xx);
                size_t off = ((size_t)b * (OUT_PAD ? 16900 : 16384) + pix) * Ctot + c0 + mbase;
                uint2 u;
                u.x = pack2(v0, v1); u.y = pack2(v2, v3);
                *reinterpret_cast<uint2*>(outN + off) = u;
            }
            if (NCHW_MODE == 1 && mbase < Cout) {
                float* oc = (float*)outC;
                size_t o = ((size_t)(b * Cout + mbase)) * 16384 + (size_t)y * 128 + xx;
                oc[o] = v0; oc[o + 16384] = v1;
                oc[o + 2 * 16384] = v2; oc[o + 3 * 16384] = v3;
            }
            if (NCHW_MODE == 2 && mbase < Cout) {
                u16* oc = (u16*)outC;
                size_t o = ((size_t)(b * Cout + mbase)) * 16384 + (size_t)y * 128 + xx;
                oc[o] = f2bf(v0); oc[o + 16384] = f2bf(v1);
                oc[o + 2 * 16384] = f2bf(v2); oc[o + 3 * 16384] = f2bf(v3);
            }
        }
    }
}

// ---------------- fused DCNv2: sample in-register + K=576 MFMA GEMM ---------
// xn : NHWC128-pad bf16 (x at ch 0..63)
// co : NCHW bf16 [b][216][16384]; ch>=144 already sigmoided
// wgt: bf16 [64][576] in sample order (g*72 + kk*8 + c)
__global__ __launch_bounds__(256, 2) void dcn_fused(
    const u16* __restrict__ xn, const u16* __restrict__ co,
    const u16* __restrict__ wgt, const float* __restrict__ bias,
    u16* __restrict__ outN) {
    __shared__ u16 lw[64 * 584];      // padded stride 584 (bank-spread)
    {
        int t = threadIdx.x;
        int o = t >> 2, chunk = t & 3;
        const u16* src = wgt + o * 576 + chunk * 144;
        u16* dst = lw + o * 584 + chunk * 144;
#pragma unroll
        for (int i = 0; i < 18; ++i)
            *reinterpret_cast<uint4*>(dst + i * 8) =
                *reinterpret_cast<const uint4*>(src + i * 8);
    }
    __syncthreads();

    const int lane = threadIdx.x & 63;
    const int wv = threadIdx.x >> 6;
    const int half = blockIdx.x & 1;
    const int y = (blockIdx.x >> 1) & 127;
    const int b = blockIdx.x >> 8;
    const int n0 = lane & 15;
    const int kq = lane >> 4;
    const int xx = half * 64 + wv * 16 + n0;
    const int p = y * 128 + xx;

    const u16* cob = co + (size_t)b * 216 * 16384 + p;
    const u16* xb = xn + (size_t)b * 16900 * 128;

    float offy[18], offx[18], mvv[18];
#pragma unroll
    for (int cs = 0; cs < 18; ++cs) {
        int gk8 = cs * 4 + kq;
        offy[cs] = bf2f(cob[(size_t)gk8 * 16384]);
        offx[cs] = bf2f(cob[(size_t)(72 + gk8) * 16384]);
        mvv[cs]  = bf2f(cob[(size_t)(144 + gk8) * 16384]);   // pre-sigmoided
    }

    f32x4 acc[4] = {};
    float w00[2], w01[2], w10[2], w11[2];
    uint4 q00[2], q01[2], q10[2], q11[2];

#define DCN_GL(cs, st) {                                                       \
        int gk8_ = (cs) * 4 + kq;                                              \
        int g_ = (gk8_ * 57) >> 9;                                             \
        int kk_ = gk8_ - 9 * g_;                                               \
        int ky_ = (kk_ * 11) >> 5;                                             \
        int kx_ = kk_ - 3 * ky_;                                               \
        float py_ = offy[cs] + (float)(ky_ - 1) + (float)y;                    \
        float px_ = offx[cs] + (float)(kx_ - 1) + (float)xx;                   \
        float y0f_ = floorf(py_), x0f_ = floorf(px_);                          \
        float wy_ = py_ - y0f_, wx_ = px_ - x0f_;                              \
        int y0_ = (int)y0f_, x0_ = (int)x0f_, y1_ = y0_ + 1, x1_ = x0_ + 1;    \
        float m00_ = ((unsigned)y0_ < 128u && (unsigned)x0_ < 128u) ? 1.f : 0.f; \
        float m01_ = ((unsigned)y0_ < 128u && (unsigned)x1_ < 128u) ? 1.f : 0.f; \
        float m10_ = ((unsigned)y1_ < 128u && (unsigned)x0_ < 128u) ? 1.f : 0.f; \
        float m11_ = ((unsigned)y1_ < 128u && (unsigned)x1_ < 128u) ? 1.f : 0.f; \
        float mv_ = mvv[cs];                                                   \
        w00[st] = (1.f - wy_) * (1.f - wx_) * m00_ * mv_;                      \
        w01[st] = (1.f - wy_) * wx_ * m01_ * mv_;                              \
        w10[st] = wy_ * (1.f - wx_) * m10_ * mv_;                              \
        w11[st] = wy_ * wx_ * m11_ * mv_;                                      \
        int y0c_ = min(max(y0_, 0), 127), y1c_ = min(max(y1_, 0), 127);        \
        int x0c_ = min(max(x0_, 0), 127), x1c_ = min(max(x1_, 0), 127);        \
        const u16* xg_ = xb + g_ * 8;                                          \
        q00[st] = *reinterpret_cast<const uint4*>(xg_ + ((size_t)(y0c_ + 1) * 130 + x0c_ + 1) * 128); \
        q01[st] = *reinterpret_cast<const uint4*>(xg_ + ((size_t)(y0c_ + 1) * 130 + x1c_ + 1) * 128); \
        q10[st] = *reinterpret_cast<const uint4*>(xg_ + ((size_t)(y1c_ + 1) * 130 + x0c_ + 1) * 128); \
        q11[st] = *reinterpret_cast<const uint4*>(xg_ + ((size_t)(y1c_ + 1) * 130 + x1c_ + 1) * 128); \
    }

#define DCN_GU(cs, st) {                                                       \
        const unsigned int* a00_ = &q00[st].x; const unsigned int* a01_ = &q01[st].x; \
        const unsigned int* a10_ = &q10[st].x; const unsigned int* a11_ = &q11[st].x; \
        float r_[8];                                                           \
        _Pragma("unroll")                                                      \
        for (int c = 0; c < 8; ++c) {                                          \
            unsigned int u00_ = a00_[c >> 1], u01_ = a01_[c >> 1];             \
            unsigned int u10_ = a10_[c >> 1], u11_ = a11_[c >> 1];             \
            int sh_ = (c & 1) * 16;                                            \
            float f00_ = bf2f((u16)(u00_ >> sh_)), f01_ = bf2f((u16)(u01_ >> sh_)); \
            float f10_ = bf2f((u16)(u10_ >> sh_)), f11_ = bf2f((u16)(u11_ >> sh_)); \
            r_[c] = w00[st] * f00_ + w01[st] * f01_ + w10[st] * f10_ + w11[st] * f11_; \
        }                                                                      \
        uint4 bu_;                                                             \
        bu_.x = pack2(r_[0], r_[1]); bu_.y = pack2(r_[2], r_[3]);              \
        bu_.z = pack2(r_[4], r_[5]); bu_.w = pack2(r_[6], r_[7]);              \
        bf16x8 bfrag_ = __builtin_bit_cast(bf16x8, bu_);                       \
        const int kcol_ = (cs) * 32 + kq * 8;                                  \
        bf16x8 a0_ = ld8(lw + (size_t)(0 * 16 + n0) * 584 + kcol_);            \
        bf16x8 a1_ = ld8(lw + (size_t)(1 * 16 + n0) * 584 + kcol_);            \
        bf16x8 a2_ = ld8(lw + (size_t)(2 * 16 + n0) * 584 + kcol_);            \
        bf16x8 a3_ = ld8(lw + (size_t)(3 * 16 + n0) * 584 + kcol_);            \
        acc[0] = __builtin_amdgcn_mfma_f32_16x16x32_bf16(a0_, bfrag_, acc[0], 0, 0, 0); \
        acc[1] = __builtin_amdgcn_mfma_f32_16x16x32_bf16(a1_, bfrag_, acc[1], 0, 0, 0); \
        acc[2] = __builtin_amdgcn_mfma_f32_16x16x32_bf16(a2_, bfrag_, acc[2], 0, 0, 0); \
        acc[3] = __builtin_amdgcn_mfma_f32_16x16x32_bf16(a3_, bfrag_, acc[3], 0, 0, 0); \
    }

    DCN_GL(0, 0)
    DCN_GL(1, 1)
#pragma unroll
    for (int cs = 0; cs < 18; cs += 2) {
        DCN_GU(cs, 0)
        if (cs + 2 < 18) DCN_GL(cs + 2, 0)
        DCN_GU(cs + 1, 1)
        if (cs + 3 < 18) DCN_GL(cs + 3, 1)
    }
#undef DCN_GL
#undef DCN_GU

    // epilogue: fea -> NHWC128-pad ch0..63
#pragma unroll
    for (int mt = 0; mt < 4; ++mt) {
        const int mbase = mt * 16 + kq * 4;
        float v0 = acc[mt][0] + bias[mbase];
        float v1 = acc[mt][1] + bias[mbase + 1];
        float v2 = acc[mt][2] + bias[mbase + 2];
        float v3 = acc[mt][3] + bias[mbase + 3];
        size_t off = ((size_t)b * 16900 + (size_t)(y + 1) * 130 + (xx + 1)) * 128 + mbase;
        uint2 u;
        u.x = pack2(v0, v1); u.y = pack2(v2, v3);
        *reinterpret_cast<uint2*>(outN + off) = u;
    }
}

// ---------------- workspace layout (bytes) ----------------------------------
#define T1_OFF 0u            /* NHWC128-pad x||y                 8,652,800 */
#define T3_OFF 8652800u      /* NHWC128-pad off1||upPrev         8,652,800 */
#define T9_OFF 17305600u     /* NHWC128-pad fea||upFea           8,652,800 */
#define T4_OFF 25958400u     /* NHWC64-pad off2                  4,326,400 */
#define T5_OFF 30284800u     /* NHWC64-pad off                   4,326,400 */
#define T6_OFF 34611200u     /* co bf16 NCHW [2][216][16384]    14,155,776 */
#define W1_OFF 48766976u
#define W2_OFF 48914432u
#define W3_OFF 49061888u
#define WF_OFF 49135616u
#define WO_OFF 49283072u     /* padded to 256 rows: 294,912 B */
#define WD_OFF 49577984u     /* ends 49,651,712 */

extern "C" void kernel_launch(void* const* d_in, const int* in_sizes, int n_in,
                              void* d_out, int out_size, void* d_ws, size_t ws_size,
                              hipStream_t stream) {
    const float* x        = (const float*)d_in[0];
    const float* y        = (const float*)d_in[1];
    const float* prev_off = (const float*)d_in[2];
    const float* prev_fea = (const float*)d_in[3];
    const float* w1 = (const float*)d_in[4];  const float* b1 = (const float*)d_in[5];
    const float* w2 = (const float*)d_in[6];  const float* b2 = (const float*)d_in[7];
    const float* w3 = (const float*)d_in[8];  const float* b3 = (const float*)d_in[9];
    const float* w_off = (const float*)d_in[10]; const float* b_off = (const float*)d_in[11];
    const float* w_dcn = (const float*)d_in[12]; const float* b_dcn = (const float*)d_in[13];
    const float* w_fea = (const float*)d_in[14]; const float* b_fea = (const float*)d_in[15];

    float* out_off = (float*)d_out;
    float* out_out = (float*)d_out + (size_t)2 * 64 * 16384;

    char* ws = (char*)d_ws;
    u16* T1 = (u16*)(ws + T1_OFF);
    u16* T3 = (u16*)(ws + T3_OFF);
    u16* T9 = (u16*)(ws + T9_OFF);
    u16* T4 = (u16*)(ws + T4_OFF);
    u16* T5 = (u16*)(ws + T5_OFF);
    u16* T6 = (u16*)(ws + T6_OFF);
    u16* wq1 = (u16*)(ws + W1_OFF);
    u16* wq2 = (u16*)(ws + W2_OFF);
    u16* wq3 = (u16*)(ws + W3_OFF);
    u16* wqf = (u16*)(ws + WF_OFF);
    u16* wqo = (u16*)(ws + WO_OFF);
    u16* wqd = (u16*)(ws + WD_OFF);
    // (wqo pad rows 216..255 never written: consumer stores masked mbase<Cout;
    //  poison bf16 is finite — deterministic, cannot leak)

    // 1. all independent preprocessing in ONE dispatch
    preproc<<<dim3(4457), dim3(256), 0, stream>>>(
        x, y, prev_off, prev_fea, w1, w2, w3, w_off, w_dcn, w_fea,
        T1, T3, T9, T4, wq1, wq2, wq3, wqo, wqd, wqf);

    // 2. conv1: concat(x,y) -> off1 (T3 ch0..63)  [256 blocks, 4px x 2K waves]
    conv_tile<128, 8, 2, 1, true, true, 0><<<dim3(256, 1), dim3(512), 0, stream>>>(
        T1, wq1, b1, T3, 0, 128, nullptr, 64);
    // 3. conv2: concat(off1, upPrev*2) -> off2 (T4)
    conv_tile<128, 8, 2, 1, true, true, 0><<<dim3(256, 1), dim3(512), 0, stream>>>(
        T3, wq2, b2, T4, 0, 64, nullptr, 64);
    // 4. conv3: off2 -> off (T5 + output0 NCHW fp32)  [4px-wave blocks, 256]
    conv_tile<64, 4, 1, 1, true, true, 1><<<dim3(256, 1), dim3(256), 0, stream>>>(
        T4, wq3, b3, T5, 0, 64, out_off, 64);
    // 5. conv_off: off -> co NCHW bf16, sigmoid on ch>=144  [4px-wave blocks]
    conv_tile<64, 4, 1, 2, false, false, 2><<<dim3(256, 4), dim3(256), 0, stream>>>(
        T5, wqo, b_off, nullptr, 0, 0, T6, 216);
    // 6. fused DCN: sample + K=576 GEMM -> fea (T9 ch0..63)
    dcn_fused<<<dim3(512), dim3(256), 0, stream>>>(T1, T6, wqd, b_dcn, T9);
    // 7. final conv: concat(fea, upFea) -> output1 NCHW fp32
    conv_tile<128, 8, 2, 1, false, false, 1><<<dim3(256, 1), dim3(512), 0, stream>>>(
        T9, wqf, b_fea, nullptr, 0, 0, out_out, 64);
}

// Round 17
// 131.667 us; speedup vs baseline: 1.1413x; 1.0025x over previous
//
#include <hip/hip_runtime.h>
#include <math.h>

typedef __bf16 bf16x8 __attribute__((ext_vector_type(8)));
typedef float f32x4 __attribute__((ext_vector_type(4)));
typedef unsigned short u16;
typedef __attribute__((address_space(3))) unsigned int lds_u32;
typedef const __attribute__((address_space(1))) unsigned int glb_u32;

// ---------------- helpers ----------------
__device__ __forceinline__ u16 f2bf(float f) {
    unsigned int u = __builtin_bit_cast(unsigned int, f);
    unsigned int r = (u + 0x7FFFu + ((u >> 16) & 1u)) >> 16;   // RNE
    return (u16)r;
}
__device__ __forceinline__ float bf2f(u16 u) {
    unsigned int v = ((unsigned int)u) << 16;
    return __builtin_bit_cast(float, v);
}
__device__ __forceinline__ unsigned int pack2(float a, float b) {
    return (unsigned int)f2bf(a) | ((unsigned int)f2bf(b) << 16);
}
__device__ __forceinline__ bf16x8 ld8(const u16* p) {
    uint4 u = *reinterpret_cast<const uint4*>(p);
    return __builtin_bit_cast(bf16x8, u);
}
__device__ __forceinline__ void gload_lds16(const u16* g, u16* l) {
#if __has_builtin(__builtin_amdgcn_global_load_lds)
    __builtin_amdgcn_global_load_lds((glb_u32*)g, (lds_u32*)l, 16, 0, 0);
#else
    *reinterpret_cast<uint4*>(l) = *reinterpret_cast<const uint4*>(g);
#endif
}

// ---------------- preproc device pieces ----------------
__device__ __forceinline__ void dev_zero(u16* base, int nimg, int C, int B, int tid) {
    int idx = B * 256 + tid;
    int c8 = C >> 3;
    int tot = nimg * 516 * c8;
    if (idx >= tot) return;
    int cb = idx % c8;
    int t = idx / c8;
    int pb = t % 516;
    int img = t / 516;
    int y, x;
    if (pb < 130)      { y = 0;        x = pb; }
    else if (pb < 260) { y = 129;      x = pb - 130; }
    else if (pb < 388) { y = pb - 259; x = 0; }
    else               { y = pb - 387; x = 129; }
    u16* d = base + ((size_t)img * 16900 + (size_t)y * 130 + x) * C + cb * 8;
    uint4 z = {0u, 0u, 0u, 0u};
    *reinterpret_cast<uint4*>(d) = z;
}

// mode 0: dst[o*9*Cin + kk*Cin + ci]; mode 1: dst[o*576 + (ci>>3)*72 + kk*8 + (ci&7)]
__device__ __forceinline__ void dev_repack(const float* w, u16* dst,
                                           int Cout, int Cin, int mode, int B, int tid) {
    int idx = B * 256 + tid;
    int total = Cout * Cin * 9;
    if (idx >= total) return;
    int kk = idx % 9;
    int t = idx / 9;
    int ci = t % Cin;
    int o = t / Cin;
    u16 v = f2bf(w[idx]);
    size_t d;
    if (mode == 0) d = (size_t)o * (9 * Cin) + kk * Cin + ci;
    else           d = (size_t)o * 576 + (ci >> 3) * 72 + kk * 8 + (ci & 7);
    dst[d] = v;
}

// NCHW->NHWC: 4 px x 8 ch per thread; 256 blocks per tensor.
__device__ __forceinline__ void dev_to_nhwc8(const float* src, u16* dst,
                                             int c0, int Ctot, int B, int tid) {
    int b = B >> 7;
    int rem = B & 127;
    int q = rem >> 4;
    int p0 = ((rem & 15) * 256 + tid) * 4;        // pixel base, 4 consecutive
    int y = p0 >> 7, x = p0 & 127;
    const float* s = src + ((size_t)b * 64 + q * 8) * 16384 + p0;
    u16* dbase = dst + (((size_t)b * 16900) + (size_t)(y + 1) * 130 + (x + 1)) * Ctot
                 + c0 + q * 8;
    float4 f[8];
#pragma unroll
    for (int c = 0; c < 8; ++c)
        f[c] = *reinterpret_cast<const float4*>(s + (size_t)c * 16384);
    const float* fp = (const float*)f;
#pragma unroll
    for (int j = 0; j < 4; ++j) {
        uint4 u;
        u.x = pack2(fp[0 * 4 + j], fp[1 * 4 + j]);
        u.y = pack2(fp[2 * 4 + j], fp[3 * 4 + j]);
        u.z = pack2(fp[4 * 4 + j], fp[5 * 4 + j]);
        u.w = pack2(fp[6 * 4 + j], fp[7 * 4 + j]);
        *reinterpret_cast<uint4*>(dbase + (size_t)j * Ctot) = u;
    }
}

// bilinear up2: 1 px x 8 ch per thread; 1024 blocks per tensor.
__device__ __forceinline__ void dev_up2_8(const float* src, u16* dst,
                                          int c0, int Ctot, float scale, int B, int tid) {
    int b = B >> 9;
    int rem = B & 511;
    int q = rem >> 6;
    int pix = (rem & 63) * 256 + tid;
    int y = pix >> 7, x = pix & 127;
    const float f = 63.0f / 127.0f;
    float cy = y * f, cx = x * f;
    float y0f = floorf(cy), x0f = floorf(cx);
    int y0 = (int)y0f, x0 = (int)x0f;
    int y1 = min(y0 + 1, 63), x1 = min(x0 + 1, 63);
    float fy = cy - y0f, fx = cx - x0f;
    float w00 = (1.f - fy) * (1.f - fx) * scale, w01 = (1.f - fy) * fx * scale;
    float w10 = fy * (1.f - fx) * scale, w11 = fy * fx * scale;
    int i00 = y0 * 64 + x0, i01 = y0 * 64 + x1, i10 = y1 * 64 + x0, i11 = y1 * 64 + x1;
    const float* s = src + ((size_t)b * 64 + q * 8) * 4096;
    float v[8];
#pragma unroll
    for (int c = 0; c < 8; ++c) {
        const float* p = s + (size_t)c * 4096;
        v[c] = w00 * p[i00] + w01 * p[i01] + w10 * p[i10] + w11 * p[i11];
    }
    uint4 u;
    u.x = pack2(v[0], v[1]); u.y = pack2(v[2], v[3]);
    u.z = pack2(v[4], v[5]); u.w = pack2(v[6], v[7]);
    u16* d = dst + (((size_t)b * 16900) + (size_t)(y + 1) * 130 + (x + 1)) * Ctot
             + c0 + q * 8;
    *reinterpret_cast<uint4*>(d) = u;
}

// ---------------- one fused preprocessing dispatch (4457 blocks) ------------
__global__ __launch_bounds__(256) void preproc(
    const float* __restrict__ x, const float* __restrict__ y,
    const float* __restrict__ prev_off, const float* __restrict__ prev_fea,
    const float* __restrict__ w1, const float* __restrict__ w2,
    const float* __restrict__ w3, const float* __restrict__ w_off,
    const float* __restrict__ w_dcn, const float* __restrict__ w_fea,
    u16* __restrict__ T1, u16* __restrict__ T3, u16* __restrict__ T9,
    u16* __restrict__ T4,
    u16* __restrict__ wq1, u16* __restrict__ wq2, u16* __restrict__ wq3,
    u16* __restrict__ wqo, u16* __restrict__ wqd, u16* __restrict__ wqf) {
    int B = blockIdx.x, tid = threadIdx.x;
    if (B < 1024) { dev_up2_8(prev_off, T3, 64, 128, 2.0f, B, tid); return; } B -= 1024;
    if (B < 1024) { dev_up2_8(prev_fea, T9, 64, 128, 1.0f, B, tid); return; } B -= 1024;
    if (B < 256) { dev_to_nhwc8(x, T1, 0, 128, B, tid); return; }       B -= 256;
    if (B < 256) { dev_to_nhwc8(y, T1, 64, 128, B, tid); return; }      B -= 256;
    if (B < 129) { dev_zero(T1, 4, 128, B, tid); return; }  B -= 129;   // T1+T3
    if (B < 65)  { dev_zero(T9, 2, 128, B, tid); return; }  B -= 65;
    if (B < 65)  { dev_zero(T4, 4, 64, B, tid); return; }   B -= 65;    // T4+T5
    if (B < 288) { dev_repack(w1, wq1, 64, 128, 0, B, tid); return; }   B -= 288;
    if (B < 288) { dev_repack(w2, wq2, 64, 128, 0, B, tid); return; }   B -= 288;
    if (B < 144) { dev_repack(w3, wq3, 64, 64, 0, B, tid); return; }    B -= 144;
    if (B < 486) { dev_repack(w_off, wqo, 216, 64, 0, B, tid); return; } B -= 486;
    if (B < 144) { dev_repack(w_dcn, wqd, 64, 64, 1, B, tid); return; } B -= 144;
    dev_repack(w_fea, wqf, 64, 128, 0, B, tid);
}

// ---------------- LDS-staged implicit-GEMM conv via MFMA (R11-proven) -------
// Wave decomposition: WAVES = PXW px-columns x KSPLIT K-slices.
// NCHW_MODE: 0 none, 1 fp32, 2 bf16
template<int CIN, int WAVES, int KSPLIT, int ACTM, bool NHWC_OUT, bool OUT_PAD, int NCHW_MODE>
__global__ __launch_bounds__(WAVES * 64) void conv_tile(
    const u16* __restrict__ in, const u16* __restrict__ wgt,
    const float* __restrict__ bias,
    u16* __restrict__ outN, int c0, int Ctot,
    void* __restrict__ outC, int Cout) {
    constexpr int T = WAVES * 64;
    constexpr int PXW = WAVES / KSPLIT;          // px-columns per block
    constexpr int BPR = 4 / PXW;                 // blocks per image row
    constexpr int KCH = CIN / KSPLIT;            // channels per wave
    constexpr int CSTEPS = KCH / 32;             // k-steps per shift per wave
    constexpr int MSK = (CIN == 128) ? 15 : 7;   // 16B-slots per row - 1
    constexpr int RSH = (CIN == 128) ? 8 : 7;    // log2(row bytes)
    __shared__ __align__(16) u16 As[2][64 * CIN];

    const int tid = threadIdx.x;
    const int lane = tid & 63;
    const int wv = tid >> 6;
    const int kslice = wv % KSPLIT;
    const int pxc = wv / KSPLIT;
    const int gx = blockIdx.x;
    const int xh = gx % BPR;
    const int y = (gx / BPR) & 127;
    const int b = gx / (BPR * 128);
    const int mblk = blockIdx.y << 6;
    const int n0 = lane & 15;
    const int kq = lane >> 4;
    const int xbase = xh * (PXW * 32) + pxc * 32;

    const u16* inB = in + (size_t)b * 16900 * CIN;

#define STAGE(ss, bf) {                                                        \
        _Pragma("unroll")                                                      \
        for (int i_ = 0; i_ < (8 * CIN) / T; ++i_) {                           \
            int L_ = (i_ * T + tid) * 16;                                      \
            int row_ = L_ >> RSH;                                              \
            int c16_ = (L_ >> 4) & MSK;                                        \
            int sc_ = c16_ ^ (row_ & MSK);                                     \
            const u16* src_ = wgt + (size_t)(mblk + row_) * (9 * CIN)          \
                              + (ss) * CIN + sc_ * 8;                          \
            gload_lds16(src_, &As[bf][L_ >> 1]);                               \
        }                                                                      \
    }

    f32x4 acc[4][2] = {};

    STAGE(0, 0)
    __syncthreads();

    for (int s = 0; s < 9; ++s) {
        const int buf = s & 1;
        if (s < 8) STAGE(s + 1, buf ^ 1)

        const int dy = s / 3, dx = s - dy * 3;
        const u16* brow = inB + ((size_t)(y + dy) * 130 + (xbase + n0 + dx)) * CIN
                          + kq * 8;
        const u16* ab = &As[buf][0];
#pragma unroll
        for (int c = 0; c < CSTEPS; ++c) {
            const int kch = kslice * KCH + c * 32;
            bf16x8 b0 = ld8(brow + kch);
            bf16x8 b1 = ld8(brow + 16 * CIN + kch);
            const int colb = (((kch >> 3) + kq) ^ (n0 & MSK)) * 8;
            bf16x8 a0 = ld8(ab + (0 * 16 + n0) * CIN + colb);
            bf16x8 a1 = ld8(ab + (1 * 16 + n0) * CIN + colb);
            bf16x8 a2 = ld8(ab + (2 * 16 + n0) * CIN + colb);
            bf16x8 a3 = ld8(ab + (3 * 16 + n0) * CIN + colb);
            acc[0][0] = __builtin_amdgcn_mfma_f32_16x16x32_bf16(a0, b0, acc[0][0], 0, 0, 0);
            acc[0][1] = __builtin_amdgcn_mfma_f32_16x16x32_bf16(a0, b1, acc[0][1], 0, 0, 0);
            acc[1][0] = __builtin_amdgcn_mfma_f32_16x16x32_bf16(a1, b0, acc[1][0], 0, 0, 0);
            acc[1][1] = __builtin_amdgcn_mfma_f32_16x16x32_bf16(a1, b1, acc[1][1], 0, 0, 0);
            acc[2][0] = __builtin_amdgcn_mfma_f32_16x16x32_bf16(a2, b0, acc[2][0], 0, 0, 0);
            acc[2][1] = __builtin_amdgcn_mfma_f32_16x16x32_bf16(a2, b1, acc[2][1], 0, 0, 0);
            acc[3][0] = __builtin_amdgcn_mfma_f32_16x16x32_bf16(a3, b0, acc[3][0], 0, 0, 0);
            acc[3][1] = __builtin_amdgcn_mfma_f32_16x16x32_bf16(a3, b1, acc[3][1], 0, 0, 0);
        }
        __syncthreads();
    }
#undef STAGE

    // 2-way K reduce (kslice 1 -> kslice 0) when split
    if (KSPLIT == 2) {
        float* red = (float*)(&As[0][0]);
        if (kslice == 1) {
#pragma unroll
            for (int mt = 0; mt < 4; ++mt)
#pragma unroll
                for (int nt = 0; nt < 2; ++nt)
                    *reinterpret_cast<f32x4*>(
                        &red[((pxc * 8) + mt * 2 + nt) * 256 + lane * 4]) = acc[mt][nt];
        }
        __syncthreads();
        if (kslice == 1) return;
#pragma unroll
        for (int mt = 0; mt < 4; ++mt)
#pragma unroll
            for (int nt = 0; nt < 2; ++nt)
                acc[mt][nt] += *reinterpret_cast<const f32x4*>(
                    &red[((pxc * 8) + mt * 2 + nt) * 256 + lane * 4]);
    }

    // epilogue: each surviving wave stores its own 32-px column, all 4 m-tiles
#pragma unroll
    for (int mt = 0; mt < 4; ++mt) {
        const int mbase = mblk + mt * 16 + kq * 4;
        float bs0 = 0.f, bs1 = 0.f, bs2 = 0.f, bs3 = 0.f;
        if (mbase < Cout) {
            bs0 = bias[mbase]; bs1 = bias[mbase + 1];
            bs2 = bias[mbase + 2]; bs3 = bias[mbase + 3];
        }
#pragma unroll
        for (int nt = 0; nt < 2; ++nt) {
            const int xx = xbase + nt * 16 + n0;
            float v0 = acc[mt][nt][0] + bs0, v1 = acc[mt][nt][1] + bs1;
            float v2 = acc[mt][nt][2] + bs2, v3 = acc[mt][nt][3] + bs3;
            if (ACTM == 1) {
                v0 = (v0 >= 0.f) ? v0 : 0.1f * v0;
                v1 = (v1 >= 0.f) ? v1 : 0.1f * v1;
                v2 = (v2 >= 0.f) ? v2 : 0.1f * v2;
                v3 = (v3 >= 0.f) ? v3 : 0.1f * v3;
            } else if (ACTM == 2) {
                if (mbase >= 144) {
                    v0 = 1.f / (1.f + expf(-v0));
                    v1 = 1.f / (1.f + expf(-v1));
                    v2 = 1.f / (1.f + expf(-v2));
                    v3 = 1.f / (1.f + expf(-v3));
                }
            }
            if (NHWC_OUT && mbase < Cout) {
                size_t pix = OUT_PAD ? ((size_t)(y + 1) * 130 + xx + 1)
                                     : ((size_t)y * 128 + xx);
                size_t off = ((size_t)b * (OUT_PAD ? 16900 : 16384) + pix) * Ctot + c0 + mbase;
                uint2 u;
                u.x = pack2(v0, v1); u.y = pack2(v2, v3);
                *reinterpret_cast<uint2*>(outN + off) = u;
            }
            if (NCHW_MODE == 1 && mbase < Cout) {
                float* oc = (float*)outC;
                size_t o = ((size_t)(b * Cout + mbase)) * 16384 + (size_t)y * 128 + xx;
                oc[o] = v0; oc[o + 16384] = v1;
                oc[o + 2 * 16384] = v2; oc[o + 3 * 16384] = v3;
            }
            if (NCHW_MODE == 2 && mbase < Cout) {
                u16* oc = (u16*)outC;
                size_t o = ((size_t)(b * Cout + mbase)) * 16384 + (size_t)y * 128 + xx;
                oc[o] = f2bf(v0); oc[o + 16384] = f2bf(v1);
                oc[o + 2 * 16384] = f2bf(v2); oc[o + 3 * 16384] = f2bf(v3);
            }
        }
    }
}

// ---------------- fused DCNv2: sample in-register + K=576 MFMA GEMM ---------
// xn : NHWC128-pad bf16 (x at ch 0..63)
// co : NCHW bf16 [b][216][16384]; ch>=144 already sigmoided
// wgt: bf16 [64][576] in sample order (g*72 + kk*8 + c)
// 4-deep gather pipeline (prefetch distance 4 k-steps ≈ 600+ cy cover)
__global__ __launch_bounds__(256, 2) void dcn_fused(
    const u16* __restrict__ xn, const u16* __restrict__ co,
    const u16* __restrict__ wgt, const float* __restrict__ bias,
    u16* __restrict__ outN) {
    __shared__ u16 lw[64 * 584];      // padded stride 584 (bank-spread)
    {
        int t = threadIdx.x;
        int o = t >> 2, chunk = t & 3;
        const u16* src = wgt + o * 576 + chunk * 144;
        u16* dst = lw + o * 584 + chunk * 144;
#pragma unroll
        for (int i = 0; i < 18; ++i)
            *reinterpret_cast<uint4*>(dst + i * 8) =
                *reinterpret_cast<const uint4*>(src + i * 8);
    }
    __syncthreads();

    const int lane = threadIdx.x & 63;
    const int wv = threadIdx.x >> 6;
    const int half = blockIdx.x & 1;
    const int y = (blockIdx.x >> 1) & 127;
    const int b = blockIdx.x >> 8;
    const int n0 = lane & 15;
    const int kq = lane >> 4;
    const int xx = half * 64 + wv * 16 + n0;
    const int p = y * 128 + xx;

    const u16* cob = co + (size_t)b * 216 * 16384 + p;
    const u16* xb = xn + (size_t)b * 16900 * 128;

    float offy[18], offx[18], mvv[18];
#pragma unroll
    for (int cs = 0; cs < 18; ++cs) {
        int gk8 = cs * 4 + kq;
        offy[cs] = bf2f(cob[(size_t)gk8 * 16384]);
        offx[cs] = bf2f(cob[(size_t)(72 + gk8) * 16384]);
        mvv[cs]  = bf2f(cob[(size_t)(144 + gk8) * 16384]);   // pre-sigmoided
    }

    f32x4 acc[4] = {};
    float w00[4], w01[4], w10[4], w11[4];
    uint4 q00[4], q01[4], q10[4], q11[4];

#define DCN_GL(cs, st) {                                                       \
        int gk8_ = (cs) * 4 + kq;                                              \
        int g_ = (gk8_ * 57) >> 9;                                             \
        int kk_ = gk8_ - 9 * g_;                                               \
        int ky_ = (kk_ * 11) >> 5;                                             \
        int kx_ = kk_ - 3 * ky_;                                               \
        float py_ = offy[cs] + (float)(ky_ - 1) + (float)y;                    \
        float px_ = offx[cs] + (float)(kx_ - 1) + (float)xx;                   \
        float y0f_ = floorf(py_), x0f_ = floorf(px_);                          \
        float wy_ = py_ - y0f_, wx_ = px_ - x0f_;                              \
        int y0_ = (int)y0f_, x0_ = (int)x0f_, y1_ = y0_ + 1, x1_ = x0_ + 1;    \
        float m00_ = ((unsigned)y0_ < 128u && (unsigned)x0_ < 128u) ? 1.f : 0.f; \
        float m01_ = ((unsigned)y0_ < 128u && (unsigned)x1_ < 128u) ? 1.f : 0.f; \
        float m10_ = ((unsigned)y1_ < 128u && (unsigned)x0_ < 128u) ? 1.f : 0.f; \
        float m11_ = ((unsigned)y1_ < 128u && (unsigned)x1_ < 128u) ? 1.f : 0.f; \
        float mv_ = mvv[cs];                                                   \
        w00[st] = (1.f - wy_) * (1.f - wx_) * m00_ * mv_;                      \
        w01[st] = (1.f - wy_) * wx_ * m01_ * mv_;                              \
        w10[st] = wy_ * (1.f - wx_) * m10_ * mv_;                              \
        w11[st] = wy_ * wx_ * m11_ * mv_;                                      \
        int y0c_ = min(max(y0_, 0), 127), y1c_ = min(max(y1_, 0), 127);        \
        int x0c_ = min(max(x0_, 0), 127), x1c_ = min(max(x1_, 0), 127);        \
        const u16* xg_ = xb + g_ * 8;                                          \
        q00[st] = *reinterpret_cast<const uint4*>(xg_ + ((size_t)(y0c_ + 1) * 130 + x0c_ + 1) * 128); \
        q01[st] = *reinterpret_cast<const uint4*>(xg_ + ((size_t)(y0c_ + 1) * 130 + x1c_ + 1) * 128); \
        q10[st] = *reinterpret_cast<const uint4*>(xg_ + ((size_t)(y1c_ + 1) * 130 + x0c_ + 1) * 128); \
        q11[st] = *reinterpret_cast<const uint4*>(xg_ + ((size_t)(y1c_ + 1) * 130 + x1c_ + 1) * 128); \
    }

#define DCN_GU(cs, st) {                                                       \
        const unsigned int* a00_ = &q00[st].x; const unsigned int* a01_ = &q01[st].x; \
        const unsigned int* a10_ = &q10[st].x; const unsigned int* a11_ = &q11[st].x; \
        float r_[8];                                                           \
        _Pragma("unroll")                                                      \
        for (int c = 0; c < 8; ++c) {                                          \
            unsigned int u00_ = a00_[c >> 1], u01_ = a01_[c >> 1];             \
            unsigned int u10_ = a10_[c >> 1], u11_ = a11_[c >> 1];             \
            int sh_ = (c & 1) * 16;                                            \
            float f00_ = bf2f((u16)(u00_ >> sh_)), f01_ = bf2f((u16)(u01_ >> sh_)); \
            float f10_ = bf2f((u16)(u10_ >> sh_)), f11_ = bf2f((u16)(u11_ >> sh_)); \
            r_[c] = w00[st] * f00_ + w01[st] * f01_ + w10[st] * f10_ + w11[st] * f11_; \
        }                                                                      \
        uint4 bu_;                                                             \
        bu_.x = pack2(r_[0], r_[1]); bu_.y = pack2(r_[2], r_[3]);              \
        bu_.z = pack2(r_[4], r_[5]); bu_.w = pack2(r_[6], r_[7]);              \
        bf16x8 bfrag_ = __builtin_bit_cast(bf16x8, bu_);                       \
        const int kcol_ = (cs) * 32 + kq * 8;                                  \
        bf16x8 a0_ = ld8(lw + (size_t)(0 * 16 + n0) * 584 + kcol_);            \
        bf16x8 a1_ = ld8(lw + (size_t)(1 * 16 + n0) * 584 + kcol_);            \
        bf16x8 a2_ = ld8(lw + (size_t)(2 * 16 + n0) * 584 + kcol_);            \
        bf16x8 a3_ = ld8(lw + (size_t)(3 * 16 + n0) * 584 + kcol_);            \
        acc[0] = __builtin_amdgcn_mfma_f32_16x16x32_bf16(a0_, bfrag_, acc[0], 0, 0, 0); \
        acc[1] = __builtin_amdgcn_mfma_f32_16x16x32_bf16(a1_, bfrag_, acc[1], 0, 0, 0); \
        acc[2] = __builtin_amdgcn_mfma_f32_16x16x32_bf16(a2_, bfrag_, acc[2], 0, 0, 0); \
        acc[3] = __builtin_amdgcn_mfma_f32_16x16x32_bf16(a3_, bfrag_, acc[3], 0, 0, 0); \
    }

    DCN_GL(0, 0)
    DCN_GL(1, 1)
    DCN_GL(2, 2)
    DCN_GL(3, 3)
#pragma unroll
    for (int cs = 0; cs < 18; ++cs) {
        DCN_GU(cs, cs & 3)
        if (cs + 4 < 18) DCN_GL(cs + 4, (cs + 4) & 3)
    }
#undef DCN_GL
#undef DCN_GU

    // epilogue: fea -> NHWC128-pad ch0..63
#pragma unroll
    for (int mt = 0; mt < 4; ++mt) {
        const int mbase = mt * 16 + kq * 4;
        float v0 = acc[mt][0] + bias[mbase];
        float v1 = acc[mt][1] + bias[mbase + 1];
        float v2 = acc[mt][2] + bias[mbase + 2];
        float v3 = acc[mt][3] + bias[mbase + 3];
        size_t off = ((size_t)b * 16900 + (size_t)(y + 1) * 130 + (xx + 1)) * 128 + mbase;
        uint2 u;
        u.x = pack2(v0, v1); u.y = pack2(v2, v3);
        *reinterpret_cast<uint2*>(outN + off) = u;
    }
}

// ---------------- workspace layout (bytes) ----------------------------------
#define T1_OFF 0u            /* NHWC128-pad x||y                 8,652,800 */
#define T3_OFF 8652800u      /* NHWC128-pad off1||upPrev         8,652,800 */
#define T9_OFF 17305600u     /* NHWC128-pad fea||upFea           8,652,800 */
#define T4_OFF 25958400u     /* NHWC64-pad off2                  4,326,400 */
#define T5_OFF 30284800u     /* NHWC64-pad off                   4,326,400 */
#define T6_OFF 34611200u     /* co bf16 NCHW [2][216][16384]    14,155,776 */
#define W1_OFF 48766976u
#define W2_OFF 48914432u
#define W3_OFF 49061888u
#define WF_OFF 49135616u
#define WO_OFF 49283072u     /* padded to 256 rows: 294,912 B */
#define WD_OFF 49577984u     /* ends 49,651,712 */

extern "C" void kernel_launch(void* const* d_in, const int* in_sizes, int n_in,
                              void* d_out, int out_size, void* d_ws, size_t ws_size,
                              hipStream_t stream) {
    const float* x        = (const float*)d_in[0];
    const float* y        = (const float*)d_in[1];
    const float* prev_off = (const float*)d_in[2];
    const float* prev_fea = (const float*)d_in[3];
    const float* w1 = (const float*)d_in[4];  const float* b1 = (const float*)d_in[5];
    const float* w2 = (const float*)d_in[6];  const float* b2 = (const float*)d_in[7];
    const float* w3 = (const float*)d_in[8];  const float* b3 = (const float*)d_in[9];
    const float* w_off = (const float*)d_in[10]; const float* b_off = (const float*)d_in[11];
    const float* w_dcn = (const float*)d_in[12]; const float* b_dcn = (const float*)d_in[13];
    const float* w_fea = (const float*)d_in[14]; const float* b_fea = (const float*)d_in[15];

    float* out_off = (float*)d_out;
    float* out_out = (float*)d_out + (size_t)2 * 64 * 16384;

    char* ws = (char*)d_ws;
    u16* T1 = (u16*)(ws + T1_OFF);
    u16* T3 = (u16*)(ws + T3_OFF);
    u16* T9 = (u16*)(ws + T9_OFF);
    u16* T4 = (u16*)(ws + T4_OFF);
    u16* T5 = (u16*)(ws + T5_OFF);
    u16* T6 = (u16*)(ws + T6_OFF);
    u16* wq1 = (u16*)(ws + W1_OFF);
    u16* wq2 = (u16*)(ws + W2_OFF);
    u16* wq3 = (u16*)(ws + W3_OFF);
    u16* wqf = (u16*)(ws + WF_OFF);
    u16* wqo = (u16*)(ws + WO_OFF);
    u16* wqd = (u16*)(ws + WD_OFF);
    // (wqo pad rows 216..255 never written: consumer stores masked mbase<Cout;
    //  poison bf16 is finite — deterministic, cannot leak)

    // 1. all independent preprocessing in ONE dispatch
    preproc<<<dim3(4457), dim3(256), 0, stream>>>(
        x, y, prev_off, prev_fea, w1, w2, w3, w_off, w_dcn, w_fea,
        T1, T3, T9, T4, wq1, wq2, wq3, wqo, wqd, wqf);

    // 2. conv1: concat(x,y) -> off1 (T3 ch0..63)  [256 blocks, 4px x 2K waves]
    conv_tile<128, 8, 2, 1, true, true, 0><<<dim3(256, 1), dim3(512), 0, stream>>>(
        T1, wq1, b1, T3, 0, 128, nullptr, 64);
    // 3. conv2: concat(off1, upPrev*2) -> off2 (T4)
    conv_tile<128, 8, 2, 1, true, true, 0><<<dim3(256, 1), dim3(512), 0, stream>>>(
        T3, wq2, b2, T4, 0, 64, nullptr, 64);
    // 4. conv3: off2 -> off (T5 + output0 NCHW fp32)  [4px-wave blocks, 256]
    conv_tile<64, 4, 1, 1, true, true, 1><<<dim3(256, 1), dim3(256), 0, stream>>>(
        T4, wq3, b3, T5, 0, 64, out_off, 64);
    // 5. conv_off: off -> co NCHW bf16, sigmoid on ch>=144  [4px-wave blocks]
    conv_tile<64, 4, 1, 2, false, false, 2><<<dim3(256, 4), dim3(256), 0, stream>>>(
        T5, wqo, b_off, nullptr, 0, 0, T6, 216);
    // 6. fused DCN: sample + K=576 GEMM -> fea (T9 ch0..63)
    dcn_fused<<<dim3(512), dim3(256), 0, stream>>>(T1, T6, wqd, b_dcn, T9);
    // 7. final conv: concat(fea, upFea) -> output1 NCHW fp32
    conv_tile<128, 8, 2, 1, false, false, 1><<<dim3(256, 1), dim3(512), 0, stream>>>(
        T9, wqf, b_fea, nullptr, 0, 0, out_out, 64);
}